// Round 17
// baseline (789.969 us; speedup 1.0000x reference)
//
#include <hip/hip_runtime.h>
#include <stdint.h>

#define B_ 8
#define C_ 256
#define N_ 4096
#define K_ 64
#define NH_ 8
#define FF_ 1024
#define L_ 3
#define M_ (B_*N_)
#define M2_ (2*M_)
#define SCALE_ 0.17677669529663687f

typedef float f32x4 __attribute__((ext_vector_type(4)));
typedef __bf16 v8bf __attribute__((ext_vector_type(8)));

__device__ __forceinline__ float b2f(unsigned short h){
  union { uint32_t u; float f; } v; v.u = ((uint32_t)h) << 16; return v.f;
}
__device__ __forceinline__ unsigned short f2b(float f){
  union { float f; uint32_t u; } v; v.f = f;
  uint32_t r = v.u + 0x7fffu + ((v.u >> 16) & 1u);
  return (unsigned short)(r >> 16);
}
__device__ __forceinline__ void gload_lds16(const void* g, void* l){
  __builtin_amdgcn_global_load_lds(
      (const __attribute__((address_space(1))) unsigned int*)g,
      (__attribute__((address_space(3))) unsigned int*)l, 16, 0, 0);
}
__device__ __forceinline__ void unpack8(uint4 v, float* o){
  o[0]=b2f((unsigned short)(v.x & 0xffff)); o[1]=b2f((unsigned short)(v.x >> 16));
  o[2]=b2f((unsigned short)(v.y & 0xffff)); o[3]=b2f((unsigned short)(v.y >> 16));
  o[4]=b2f((unsigned short)(v.z & 0xffff)); o[5]=b2f((unsigned short)(v.z >> 16));
  o[6]=b2f((unsigned short)(v.w & 0xffff)); o[7]=b2f((unsigned short)(v.w >> 16));
}

// ---------------- all weight conversions in one dispatch ----------------
__global__ __launch_bounds__(256) void k_convall(
    const float* s0, unsigned short* d0, int n0_,
    const float* s1, unsigned short* d1, int n1_,
    const float* s2, unsigned short* d2, int n2_,
    const float* s3, unsigned short* d3, int n3_,
    const float* s4, unsigned short* d4, int n4_,
    const float* s5, unsigned short* d5, int n5_){
  const float* s; unsigned short* d; int n;
  switch (blockIdx.y){
    case 0: s=s0; d=d0; n=n0_; break;
    case 1: s=s1; d=d1; n=n1_; break;
    case 2: s=s2; d=d2; n=n2_; break;
    case 3: s=s3; d=d3; n=n3_; break;
    case 4: s=s4; d=d4; n=n4_; break;
    default:s=s5; d=d5; n=n5_; break;
  }
  int i4 = (blockIdx.x*256 + threadIdx.x)*4;
  if (i4 >= n) return;
  float4 v = *(const float4*)(s + i4);
  uint32_t p0 = (uint32_t)f2b(v.x) | ((uint32_t)f2b(v.y) << 16);
  uint32_t p1 = (uint32_t)f2b(v.z) | ((uint32_t)f2b(v.w) << 16);
  *(uint2*)(d + i4) = make_uint2(p0, p1);
}

// ---------------- build xcT ----------------
__global__ __launch_bounds__(256) void k_build_xcT(const float* __restrict__ x,
                                                   const float* __restrict__ y,
                                                   unsigned short* __restrict__ xcT){
  __shared__ float t[32][33];
  int b = blockIdx.z;
  int n0 = blockIdx.x*32, c0 = blockIdx.y*32;
  int tx = threadIdx.x, ty = threadIdx.y;
  const float* src = (c0 < 256) ? (x + ((size_t)b*256 + c0)*N_)
                                : (y + ((size_t)b*256 + (c0-256))*N_);
  #pragma unroll
  for (int i = 0; i < 4; i++){
    int cl = ty*4 + i;
    t[cl][tx] = src[(size_t)cl*N_ + n0 + tx];
  }
  __syncthreads();
  #pragma unroll
  for (int i = 0; i < 4; i++){
    int nl = ty*4 + i;
    xcT[((size_t)b*N_ + n0 + nl)*512 + c0 + tx] = f2b(t[tx][nl]);
  }
}

// ---------------- feat mirrors ----------------
__global__ __launch_bounds__(256) void k_featmir(const float* __restrict__ featT,
                                                 unsigned short* __restrict__ featbf,
                                                 unsigned short* __restrict__ featC){
  __shared__ float t[32][33];
  int b = blockIdx.z;
  int n0 = blockIdx.x*32, c0 = blockIdx.y*32;
  int tx = threadIdx.x, ty = threadIdx.y;
  #pragma unroll
  for (int i = 0; i < 4; i++){
    int nl = ty*4 + i;
    size_t m = (size_t)b*N_ + n0 + nl;
    float v = featT[m*256 + c0 + tx];
    t[nl][tx] = v;
    featbf[m*256 + c0 + tx] = f2b(v);
  }
  __syncthreads();
  #pragma unroll
  for (int i = 0; i < 4; i++){
    int cl = ty*4 + i;
    featC[((size_t)b*256 + c0 + cl)*(size_t)N_ + n0 + tx] = f2b(t[tx][cl]);
  }
}

// ---------------- combined saliency vector (fp64) ----------------
__global__ __launch_bounds__(512) void k_compute_u(const float* __restrict__ sal_w,
                                                   const float* __restrict__ proj_w,
                                                   const float* __restrict__ proj_b,
                                                   const float* __restrict__ sal_b,
                                                   double* __restrict__ u){
  int c2 = threadIdx.x;
  double acc = 0.0;
  for (int c = 0; c < 256; ++c)
    acc += (double)sal_w[c] * (double)proj_w[(size_t)c*512 + c2];
  u[c2] = acc;
  if (c2 == 0){
    double s0 = (double)sal_b[0];
    for (int c = 0; c < 256; ++c) s0 += (double)sal_w[c] * (double)proj_b[c];
    u[512] = s0;
  }
}

// ---------------- sal partials ----------------
__global__ __launch_bounds__(256) void k_sal_part(const float* __restrict__ x,
                                                  const float* __restrict__ y,
                                                  const double* __restrict__ u,
                                                  double* __restrict__ part){
  int pix = blockIdx.x*256 + threadIdx.x;
  int cc = blockIdx.y;
  int b = pix >> 12, n = pix & 4095;
  int c0 = cc*32;
  const float* src = (c0 < 256) ? (x + ((size_t)b*256 + c0)*N_ + n)
                                : (y + ((size_t)b*256 + (c0-256))*N_ + n);
  const double* uu = u + c0;
  double acc = 0.0;
  #pragma unroll 8
  for (int c = 0; c < 32; ++c) acc += uu[c] * (double)src[(size_t)c*N_];
  part[(size_t)cc*32768 + pix] = acc;
}

// ---------------- sal reduce ----------------
__global__ __launch_bounds__(256) void k_sal_red(const double* __restrict__ part,
                                                 const double* __restrict__ u,
                                                 float* __restrict__ heat,
                                                 int* __restrict__ counts){
  int pix = blockIdx.x*256 + threadIdx.x;
  int b = pix >> 12;
  double acc = u[512];
  #pragma unroll
  for (int cc = 0; cc < 16; cc++) acc += part[(size_t)cc*32768 + pix];
  float hf = (float)(1.0 / (1.0 + exp(-acc)));
  heat[pix] = hf;
  unsigned long long mfg = __ballot(hf >= 0.5f);
  unsigned long long mbg = __ballot(hf < 0.5f);
  if ((threadIdx.x & 63) == 0){
    atomicAdd(&counts[b*2+0], (int)__popcll(mfg));
    atomicAdd(&counts[b*2+1], (int)__popcll(mbg));
  }
}

// ---------------- bf16 MFMA GEMM (2-phase dbuf, XOR swizzle) ----------------
template<int EPI>
__global__ __launch_bounds__(256) void k_gemm_bt(
    const unsigned short* __restrict__ A, const unsigned short* __restrict__ W,
    const float* __restrict__ bias, void* __restrict__ out,
    int M, int N, int K){
  __shared__ unsigned short smem[2][2][128*64];
  int tid = threadIdx.x;
  int w = tid >> 6, l = tid & 63;
  int m0 = blockIdx.x * 128, n0 = blockIdx.y * 128;
  int wr = w >> 1, wc = w & 1;
  int lr = l & 15, lk = l >> 4;
  f32x4 acc[4][4] = {};
  int nt = K >> 6;
  #pragma unroll
  for (int i = 0; i < 4; i++){
    int idx = i*256 + tid;
    int row = idx >> 3, su = ((idx & 7) ^ (row & 7))*8;
    gload_lds16(A + (size_t)(m0+row)*K + su, &smem[0][0][idx*8]);
    gload_lds16(W + (size_t)(n0+row)*K + su, &smem[0][1][idx*8]);
  }
  __syncthreads();
  for (int t = 0; t < nt; ++t){
    int cur = t & 1;
    if (t + 1 < nt){
      int k0 = (t + 1) << 6;
      #pragma unroll
      for (int i = 0; i < 4; i++){
        int idx = i*256 + tid;
        int row = idx >> 3, su = ((idx & 7) ^ (row & 7))*8;
        gload_lds16(A + (size_t)(m0+row)*K + k0 + su, &smem[cur^1][0][idx*8]);
        gload_lds16(W + (size_t)(n0+row)*K + k0 + su, &smem[cur^1][1][idx*8]);
      }
    }
    const unsigned short* ldsA = smem[cur][0];
    const unsigned short* ldsB = smem[cur][1];
    #pragma unroll
    for (int kk = 0; kk < 2; kk++){
      v8bf af[4], bfr[4];
      #pragma unroll
      for (int f = 0; f < 4; f++){
        int ra = wr*64 + f*16 + lr;
        int rb2 = wc*64 + f*16 + lr;
        int u = kk*4 + lk;
        af[f]  = *(const v8bf*)(&ldsA[ra*64 + ((u ^ (ra&7))<<3)]);
        bfr[f] = *(const v8bf*)(&ldsB[rb2*64 + ((u ^ (rb2&7))<<3)]);
      }
      #pragma unroll
      for (int fi = 0; fi < 4; fi++)
        #pragma unroll
        for (int fj = 0; fj < 4; fj++)
          acc[fi][fj] = __builtin_amdgcn_mfma_f32_16x16x32_bf16(af[fi], bfr[fj], acc[fi][fj], 0, 0, 0);
    }
    __syncthreads();
  }
  if (EPI == 1 || EPI == 2){
    unsigned short* st = &smem[0][0][0];
    #pragma unroll
    for (int fj = 0; fj < 4; fj++){
      int col = wc*64 + fj*16 + lr;
      float bv = bias[n0 + col];
      #pragma unroll
      for (int fi = 0; fi < 4; fi++){
        int rl = wr*64 + fi*16 + lk*4;
        #pragma unroll
        for (int r = 0; r < 4; r++){
          float v = acc[fi][fj][r] + bv;
          if (EPI == 1) v = fmaxf(v, 0.f);
          st[(rl + r)*136 + col] = f2b(v);
        }
      }
    }
    __syncthreads();
    #pragma unroll
    for (int it = 0; it < 8; it++){
      int idx = it*256 + tid;
      int row = idx >> 4, c8 = (idx & 15)*8;
      *(uint4*)((unsigned short*)out + (size_t)(m0+row)*N + n0 + c8)
          = *(const uint4*)&st[row*136 + c8];
    }
  } else {
    #pragma unroll
    for (int fj = 0; fj < 4; fj++){
      int col = n0 + wc*64 + fj*16 + lr;
      float bv = bias[col];
      #pragma unroll
      for (int fi = 0; fi < 4; fi++){
        int rb = m0 + wr*64 + fi*16 + lk*4;
        #pragma unroll
        for (int r = 0; r < 4; r++){
          float v = acc[fi][fj][r] + bv;
          ((float*)out)[(size_t)(rb + r)*N + col] = v;
        }
      }
    }
  }
}

// ---------------- merged QKV projection (both sides), one dispatch ----------------
__global__ __launch_bounds__(256) void k_qkv(
    const unsigned short* __restrict__ qin0, const unsigned short* __restrict__ qin1,
    const unsigned short* __restrict__ pool2, const unsigned short* __restrict__ aiw,
    const float* __restrict__ aib, int sl0,
    unsigned short* __restrict__ qq2, unsigned short* __restrict__ kk2,
    unsigned short* __restrict__ vvT2){
  __shared__ unsigned short smem[2][2][128*64];
  int tid = threadIdx.x;
  int w = tid >> 6, l = tid & 63;
  int bx = blockIdx.x, n0 = blockIdx.y*128;
  int wr = w >> 1, wc = w & 1;
  int lr = l & 15, lk = l >> 4;
  const unsigned short* Aptr; size_t abase;
  const unsigned short* W; const float* bias;
  int mode, m0;
  if (bx < 512){
    mode = 0; m0 = bx*128;
    int side = (m0 >= M_) ? 1 : 0;
    Aptr = side ? qin1 : qin0; abase = (size_t)(m0 - side*M_);
    int sl = sl0 + side*L_;
    W = aiw + (size_t)sl*768*C_;
    bias = aib + (size_t)sl*768;
  } else if (bx < 520){
    mode = 1; m0 = (bx - 512)*128;
    int side = (m0 >= 512) ? 1 : 0;
    Aptr = pool2; abase = (size_t)m0;
    int sl = sl0 + side*L_;
    W = aiw + (size_t)sl*768*C_ + (size_t)256*C_;
    bias = aib + (size_t)sl*768 + 256;
  } else {
    mode = 2; m0 = (bx - 520)*128;
    int side = (m0 >= 512) ? 1 : 0;
    Aptr = pool2; abase = (size_t)m0;
    int sl = sl0 + side*L_;
    W = aiw + (size_t)sl*768*C_ + (size_t)512*C_;
    bias = aib + (size_t)sl*768 + 512;
  }
  f32x4 acc[4][4] = {};
  #pragma unroll
  for (int i = 0; i < 4; i++){
    int idx = i*256 + tid;
    int row = idx >> 3, su = ((idx & 7) ^ (row & 7))*8;
    gload_lds16(Aptr + (abase+row)*256 + su, &smem[0][0][idx*8]);
    gload_lds16(W + (size_t)(n0+row)*256 + su, &smem[0][1][idx*8]);
  }
  __syncthreads();
  for (int t = 0; t < 4; ++t){
    int cur = t & 1;
    if (t + 1 < 4){
      int k0 = (t + 1) << 6;
      #pragma unroll
      for (int i = 0; i < 4; i++){
        int idx = i*256 + tid;
        int row = idx >> 3, su = ((idx & 7) ^ (row & 7))*8;
        gload_lds16(Aptr + (abase+row)*256 + k0 + su, &smem[cur^1][0][idx*8]);
        gload_lds16(W + (size_t)(n0+row)*256 + k0 + su, &smem[cur^1][1][idx*8]);
      }
    }
    const unsigned short* ldsA = smem[cur][0];
    const unsigned short* ldsB = smem[cur][1];
    #pragma unroll
    for (int kk = 0; kk < 2; kk++){
      v8bf af[4], bfr[4];
      #pragma unroll
      for (int f = 0; f < 4; f++){
        int ra = wr*64 + f*16 + lr;
        int rb2 = wc*64 + f*16 + lr;
        int u = kk*4 + lk;
        af[f]  = *(const v8bf*)(&ldsA[ra*64 + ((u ^ (ra&7))<<3)]);
        bfr[f] = *(const v8bf*)(&ldsB[rb2*64 + ((u ^ (rb2&7))<<3)]);
      }
      #pragma unroll
      for (int fi = 0; fi < 4; fi++)
        #pragma unroll
        for (int fj = 0; fj < 4; fj++)
          acc[fi][fj] = __builtin_amdgcn_mfma_f32_16x16x32_bf16(af[fi], bfr[fj], acc[fi][fj], 0, 0, 0);
    }
    __syncthreads();
  }
  if (mode == 2){
    int side = (m0 >= 512) ? 1 : 0;
    #pragma unroll
    for (int fj = 0; fj < 4; fj++){
      int col = n0 + wc*64 + fj*16 + lr;
      float bv = bias[col];
      #pragma unroll
      for (int fi = 0; fi < 4; fi++){
        int rb = m0 + wr*64 + fi*16 + lk*4;
        #pragma unroll
        for (int r = 0; r < 4; r++){
          float v = acc[fi][fj][r] + bv;
          int rl = rb + r - side*512;
          vvT2[(size_t)side*(B_*C_*K_) + ((size_t)(rl>>6)*256 + col)*64 + (rl&63)] = f2b(v);
        }
      }
    }
  } else {
    unsigned short* outp = (mode == 0) ? qq2 : kk2;
    unsigned short* st = &smem[0][0][0];
    #pragma unroll
    for (int fj = 0; fj < 4; fj++){
      int col = wc*64 + fj*16 + lr;
      float bv = bias[n0 + col];
      #pragma unroll
      for (int fi = 0; fi < 4; fi++){
        int rl = wr*64 + fi*16 + lk*4;
        #pragma unroll
        for (int r = 0; r < 4; r++)
          st[(rl + r)*136 + col] = f2b(acc[fi][fj][r] + bv);
      }
    }
    __syncthreads();
    #pragma unroll
    for (int it = 0; it < 8; it++){
      int idx = it*256 + tid;
      int row = idx >> 4, c8 = (idx & 15)*8;
      *(uint4*)(outp + (size_t)(m0+row)*256 + n0 + c8) = *(const uint4*)&st[row*136 + c8];
    }
  }
}

// ---------------- attn-out GEMM + residual + LayerNorm1 fused (both sides) ----------------
template<int RF32>
__global__ __launch_bounds__(512) void k_gemm_ln(
    const unsigned short* __restrict__ A, const unsigned short* __restrict__ aow,
    const float* __restrict__ aob, const void* __restrict__ resid,
    const float* __restrict__ n1g, const float* __restrict__ n1b, int sl0,
    unsigned short* __restrict__ qout){
  __shared__ unsigned short smem[49152];
  int tid = threadIdx.x;
  int w = tid >> 6, l = tid & 63;
  int m0 = blockIdx.x * 128;
  int side = (m0 >= M_) ? 1 : 0;
  int sl = sl0 + side*L_;
  const unsigned short* W = aow + (size_t)sl*C_*C_;
  const float* bias = aob + (size_t)sl*C_;
  const float* g = n1g + (size_t)sl*C_;
  const float* bta = n1b + (size_t)sl*C_;
  size_t rbase = RF32 ? (size_t)(m0 - side*M_) : (size_t)m0;
  int wm = w >> 2, wf = w & 3;
  int lr = l & 15, lk = l >> 4;
  f32x4 acc[4][4] = {};
  #pragma unroll
  for (int i = 0; i < 2; i++){
    int idx = i*512 + tid;
    int row = idx >> 3, su = ((idx & 7) ^ (row & 7))*8;
    gload_lds16(A + (size_t)(m0+row)*256 + su, &smem[idx*8]);
  }
  #pragma unroll
  for (int i = 0; i < 4; i++){
    int idx = i*512 + tid;
    int row = idx >> 3, su = ((idx & 7) ^ (row & 7))*8;
    gload_lds16(W + (size_t)row*256 + su, &smem[8192 + idx*8]);
  }
  __syncthreads();
  for (int t = 0; t < 4; ++t){
    int cur = t & 1;
    if (t + 1 < 4){
      int k0 = (t + 1) << 6;
      unsigned short* bA = smem + (cur^1)*24576;
      unsigned short* bB = bA + 8192;
      #pragma unroll
      for (int i = 0; i < 2; i++){
        int idx = i*512 + tid;
        int row = idx >> 3, su = ((idx & 7) ^ (row & 7))*8;
        gload_lds16(A + (size_t)(m0+row)*256 + k0 + su, &bA[idx*8]);
      }
      #pragma unroll
      for (int i = 0; i < 4; i++){
        int idx = i*512 + tid;
        int row = idx >> 3, su = ((idx & 7) ^ (row & 7))*8;
        gload_lds16(W + (size_t)row*256 + k0 + su, &bB[idx*8]);
      }
    }
    const unsigned short* bA = smem + cur*24576;
    const unsigned short* bB = bA + 8192;
    #pragma unroll
    for (int kk = 0; kk < 2; kk++){
      v8bf af[4], wb[4];
      int u = kk*4 + lk;
      #pragma unroll
      for (int f = 0; f < 4; f++){
        int ra = wm*64 + f*16 + lr;
        af[f] = *(const v8bf*)&bA[ra*64 + ((u ^ (ra&7))<<3)];
      }
      #pragma unroll
      for (int f = 0; f < 4; f++){
        int rc = wf*64 + f*16 + lr;
        wb[f] = *(const v8bf*)&bB[rc*64 + ((u ^ (rc&7))<<3)];
      }
      #pragma unroll
      for (int fi = 0; fi < 4; fi++)
        #pragma unroll
        for (int fc = 0; fc < 4; fc++)
          acc[fi][fc] = __builtin_amdgcn_mfma_f32_16x16x32_bf16(af[fi], wb[fc], acc[fi][fc], 0, 0, 0);
    }
    __syncthreads();
  }
  unsigned short* st = smem;
  #pragma unroll
  for (int fc = 0; fc < 4; fc++){
    int col = wf*64 + fc*16 + lr;
    float bv = bias[col];
    #pragma unroll
    for (int fi = 0; fi < 4; fi++){
      int rl = wm*64 + fi*16 + lk*4;
      #pragma unroll
      for (int r = 0; r < 4; r++)
        st[(rl + r)*264 + col] = f2b(acc[fi][fc][r] + bv);
    }
  }
  __syncthreads();
  int row = tid >> 2, seg = tid & 3;
  float xv[64];
  #pragma unroll
  for (int j = 0; j < 8; j++){
    int cu = seg*8 + j;
    uint4 dv = *(const uint4*)&st[row*264 + cu*8];
    float dd[8];
    unpack8(dv, dd);
    if (RF32){
      const float* rp = (const float*)resid + (rbase+row)*256 + cu*8;
      float4 r0 = *(const float4*)rp, r1 = *(const float4*)(rp + 4);
      xv[j*8+0] = r0.x + dd[0]; xv[j*8+1] = r0.y + dd[1];
      xv[j*8+2] = r0.z + dd[2]; xv[j*8+3] = r0.w + dd[3];
      xv[j*8+4] = r1.x + dd[4]; xv[j*8+5] = r1.y + dd[5];
      xv[j*8+6] = r1.z + dd[6]; xv[j*8+7] = r1.w + dd[7];
    } else {
      uint4 rv = *(const uint4*)((const unsigned short*)resid + (rbase+row)*256 + cu*8);
      float rr[8];
      unpack8(rv, rr);
      #pragma unroll
      for (int e = 0; e < 8; e++) xv[j*8+e] = rr[e] + dd[e];
    }
  }
  float s = 0.f, q = 0.f;
  #pragma unroll
  for (int i2 = 0; i2 < 64; i2++){ s += xv[i2]; q += xv[i2]*xv[i2]; }
  s += __shfl_xor(s, 1); s += __shfl_xor(s, 2);
  q += __shfl_xor(q, 1); q += __shfl_xor(q, 2);
  float mean = s * (1.0f/256.0f);
  float rstd = 1.0f / sqrtf(q*(1.0f/256.0f) - mean*mean + 1e-5f);
  #pragma unroll
  for (int j = 0; j < 8; j++){
    int c0 = seg*64 + j*8;
    float4 g0 = *(const float4*)(g + c0), g1 = *(const float4*)(g + c0 + 4);
    float4 b0 = *(const float4*)(bta + c0), b1 = *(const float4*)(bta + c0 + 4);
    uint4 ov;
    ov.x = (uint32_t)f2b((xv[j*8+0]-mean)*rstd*g0.x + b0.x)
         | ((uint32_t)f2b((xv[j*8+1]-mean)*rstd*g0.y + b0.y) << 16);
    ov.y = (uint32_t)f2b((xv[j*8+2]-mean)*rstd*g0.z + b0.z)
         | ((uint32_t)f2b((xv[j*8+3]-mean)*rstd*g0.w + b0.w) << 16);
    ov.z = (uint32_t)f2b((xv[j*8+4]-mean)*rstd*g1.x + b1.x)
         | ((uint32_t)f2b((xv[j*8+5]-mean)*rstd*g1.y + b1.y) << 16);
    ov.w = (uint32_t)f2b((xv[j*8+6]-mean)*rstd*g1.z + b1.z)
         | ((uint32_t)f2b((xv[j*8+7]-mean)*rstd*g1.w + b1.w) << 16);
    *(uint4*)&st[row*264 + c0] = ov;
  }
  __syncthreads();
  #pragma unroll
  for (int it = 0; it < 8; it++){
    int idx = it*512 + tid;
    int rw = idx >> 5, c8 = (idx & 31)*8;
    *(uint4*)(qout + (size_t)(m0+rw)*256 + c8) = *(const uint4*)&st[rw*264 + c8];
  }
}

// ---------------- fused FFN (round-16 proven) + sH bit3-aware XOR key ----------------
// key = (mr ^ (mr>>3)) & 7 distinguishes rows 8 apart (row stride 128B = bank
// wrap), breaking the measured 4-way sH write conflict. Same involution on
// write & read -> bit-identical math.
__global__ __launch_bounds__(512) void k_ffn(
    const unsigned short* __restrict__ qb, const unsigned short* __restrict__ f1w,
    const float* __restrict__ f1b, const unsigned short* __restrict__ f2w,
    const float* __restrict__ f2b_, int sl0, unsigned short* __restrict__ outb){
  __shared__ unsigned short smem[73728];
  unsigned short* sA  = smem;
  unsigned short* sW1 = smem + 32768;
  unsigned short* sW2 = smem + 49152;
  unsigned short* sH  = smem + 65536;
  int tid = threadIdx.x;
  int w = tid >> 6, l = tid & 63;
  int m0 = blockIdx.x * 128;
  int side = (m0 >= M_) ? 1 : 0;
  int sl = sl0 + side*L_;
  const unsigned short* W1g = f1w + (size_t)sl*FF_*C_;
  const float* b1g = f1b + (size_t)sl*FF_;
  const unsigned short* W2g = f2w + (size_t)sl*C_*FF_;
  const float* b2g = f2b_ + (size_t)sl*C_;
  int wm = w >> 2, wf = w & 3;
  int lr = l & 15, lk = l >> 4;

  #pragma unroll
  for (int i = 0; i < 8; i++){
    int idx = i*512 + tid;
    int row = idx >> 5, g = idx & 31;
    int su = (g & 24) | ((g & 7) ^ (row & 7));
    gload_lds16(qb + (size_t)(m0+row)*256 + su*8, &sA[idx*8]);
  }
  #pragma unroll
  for (int i = 0; i < 4; i++){
    int idx = i*512 + tid;
    int row = idx >> 5, g = idx & 31;
    int su = (g & 24) | ((g & 7) ^ (row & 7));
    gload_lds16(W1g + (size_t)row*256 + su*8, &sW1[idx*8]);
  }
  #pragma unroll
  for (int i = 0; i < 4; i++){
    int idx = i*512 + tid;
    int row = idx >> 3, g = idx & 7;
    int su = g ^ (row & 7);
    gload_lds16(W2g + (size_t)row*1024 + su*8, &sW2[idx*8]);
  }
  __syncthreads();

  f32x4 acc[4][4] = {};
  for (int cc = 0; cc < 16; ++cc){
    f32x4 hacc[4] = {};
    #pragma unroll
    for (int ks = 0; ks < 8; ks++){
      int g = ks*4 + lk;
      int rf = wf*16 + lr;
      v8bf bf1 = *(const v8bf*)&sW1[rf*256 + (((g & 24) | ((g & 7) ^ (rf & 7)))<<3)];
      #pragma unroll
      for (int f = 0; f < 4; f++){
        int ra = wm*64 + f*16 + lr;
        v8bf af = *(const v8bf*)&sA[ra*256 + (((g & 24) | ((g & 7) ^ (ra & 7)))<<3)];
        hacc[f] = __builtin_amdgcn_mfma_f32_16x16x32_bf16(af, bf1, hacc[f], 0, 0, 0);
      }
    }
    {
      int fc = wf*16 + lr;
      float b1v = b1g[cc*64 + fc];
      #pragma unroll
      for (int fi = 0; fi < 4; fi++){
        int mr0 = wm*64 + fi*16 + lk*4;
        #pragma unroll
        for (int r = 0; r < 4; r++){
          float v = fmaxf(hacc[fi][r] + b1v, 0.f);
          int mr = mr0 + r;
          int key = (mr ^ (mr >> 3)) & 7;
          sH[mr*64 + (((fc >> 3) ^ key)<<3) + (fc & 7)] = f2b(v);
        }
      }
    }
    __syncthreads();
    if (cc + 1 < 16){
      int f0n = (cc+1)*64;
      #pragma unroll
      for (int i = 0; i < 4; i++){
        int idx = i*512 + tid;
        int row = idx >> 5, g = idx & 31;
        int su = (g & 24) | ((g & 7) ^ (row & 7));
        gload_lds16(W1g + (size_t)(f0n+row)*256 + su*8, &sW1[idx*8]);
      }
    }
    #pragma unroll
    for (int ks2 = 0; ks2 < 2; ks2++){
      int g = ks2*4 + lk;
      v8bf ha[4], wb[4];
      #pragma unroll
      for (int f = 0; f < 4; f++){
        int rh = wm*64 + f*16 + lr;
        int key = (rh ^ (rh >> 3)) & 7;
        ha[f] = *(const v8bf*)&sH[rh*64 + ((g ^ key)<<3)];
      }
      #pragma unroll
      for (int f = 0; f < 4; f++){
        int rc = wf*64 + f*16 + lr;
        wb[f] = *(const v8bf*)&sW2[rc*64 + ((g ^ (rc & 7))<<3)];
      }
      #pragma unroll
      for (int fi = 0; fi < 4; fi++)
        #pragma unroll
        for (int fc = 0; fc < 4; fc++)
          acc[fi][fc] = __builtin_amdgcn_mfma_f32_16x16x32_bf16(ha[fi], wb[fc], acc[fi][fc], 0, 0, 0);
    }
    __syncthreads();
    if (cc + 1 < 16){
      int f0n = (cc+1)*64;
      #pragma unroll
      for (int i = 0; i < 4; i++){
        int idx = i*512 + tid;
        int row = idx >> 3, g = idx & 7;
        int su = g ^ (row & 7);
        gload_lds16(W2g + (size_t)row*1024 + f0n + su*8, &sW2[idx*8]);
      }
    }
  }
  unsigned short* st = smem;
  #pragma unroll
  for (int fc = 0; fc < 4; fc++){
    int col = wf*64 + fc*16 + lr;
    float bv = b2g[col];
    #pragma unroll
    for (int fi = 0; fi < 4; fi++){
      int rl = wm*64 + fi*16 + lk*4;
      #pragma unroll
      for (int r = 0; r < 4; r++)
        st[(rl + r)*264 + col] = f2b(acc[fi][fc][r] + bv);
    }
  }
  __syncthreads();
  #pragma unroll
  for (int it = 0; it < 8; it++){
    int idx = it*512 + tid;
    int row = idx >> 5, c8 = (idx & 31)*8;
    *(uint4*)(outb + (size_t)(m0+row)*256 + c8) = *(const uint4*)&st[row*264 + c8];
  }
}

// ---------------- swh ----------------
__global__ __launch_bounds__(256) void k_swh(const float* __restrict__ g_all,
                                             const float* __restrict__ heat,
                                             const float* __restrict__ soft_b,
                                             unsigned short* __restrict__ swh){
  __shared__ float gl[64*129];
  __shared__ float hml[64];
  int tid = threadIdx.x;
  int blk = blockIdx.x;
  size_t m0 = (size_t)blk*64;
  int b = (int)(m0 >> 12), n0 = (int)(m0 & 4095);
  #pragma unroll
  for (int i = 0; i < 32; i++){
    int idx = i*256 + tid;
    int row = idx >> 7, col = idx & 127;
    gl[row*129 + col] = g_all[(m0 + row)*128 + col];
  }
  if (tid < 64) hml[tid] = heat[(size_t)b*4096 + n0 + tid];
  __syncthreads();
  int k = tid >> 2, j0 = (tid & 3)*16;
  #pragma unroll
  for (int s = 0; s < 2; s++){
    float sb = soft_b[s*64 + k];
    unsigned short vals[16];
    #pragma unroll
    for (int j = 0; j < 16; j++){
      int n = j0 + j;
      float h = hml[n];
      float hm = s ? (1.0f - h) : h;
      vals[j] = f2b((gl[n*129 + s*64 + k]*hm + sb)*hm);
    }
    unsigned short* dst = swh + (((size_t)b*2 + s)*64 + k)*4096 + n0 + j0;
    uint4 o0, o1;
    o0.x = vals[0] | ((uint32_t)vals[1]<<16);  o0.y = vals[2] | ((uint32_t)vals[3]<<16);
    o0.z = vals[4] | ((uint32_t)vals[5]<<16);  o0.w = vals[6] | ((uint32_t)vals[7]<<16);
    o1.x = vals[8] | ((uint32_t)vals[9]<<16);  o1.y = vals[10]| ((uint32_t)vals[11]<<16);
    o1.z = vals[12]| ((uint32_t)vals[13]<<16); o1.w = vals[14]| ((uint32_t)vals[15]<<16);
    *(uint4*)dst = o0;
    *(uint4*)(dst + 8) = o1;
  }
}

// ---------------- pool GEMM (split-K) ----------------
__global__ __launch_bounds__(256) void k_poolgemm(
    const unsigned short* __restrict__ swh, const unsigned short* __restrict__ featC,
    float* __restrict__ pp){
  __shared__ unsigned short ldsA[128*64];
  __shared__ unsigned short ldsB[128*64];
  int tid = threadIdx.x;
  int w = tid >> 6, l = tid & 63;
  int kc = blockIdx.x, nt = blockIdx.y, b = blockIdx.z;
  int wr = w >> 1, wc = w & 1;
  int lr = l & 15, lk = l >> 4;
  const unsigned short* A = swh  + (size_t)b*128*4096 + kc*512;
  const unsigned short* W = featC + ((size_t)b*256 + nt*128)*4096 + kc*512;
  f32x4 acc[4][4] = {};
  for (int k0 = 0; k0 < 512; k0 += 64){
    #pragma unroll
    for (int i = 0; i < 4; i++){
      int idx = i*256 + tid;
      int row = idx >> 3, su = (idx & 7) ^ (row & 7);
      gload_lds16(A + (size_t)row*4096 + k0 + su*8, &ldsA[idx*8]);
    }
    #pragma unroll
    for (int i = 0; i < 4; i++){
      int idx = i*256 + tid;
      int row = idx >> 3, su = (idx & 7) ^ (row & 7);
      gload_lds16(W + (size_t)row*4096 + k0 + su*8, &ldsB[idx*8]);
    }
    __syncthreads();
    #pragma unroll
    for (int kk = 0; kk < 2; kk++){
      v8bf af[4], bfr[4];
      #pragma unroll
      for (int f = 0; f < 4; f++){
        int ra = wr*64 + f*16 + lr;
        int rb2 = wc*64 + f*16 + lr;
        int u = kk*4 + lk;
        af[f]  = *(const v8bf*)(&ldsA[ra*64 + ((u ^ (ra&7))<<3)]);
        bfr[f] = *(const v8bf*)(&ldsB[rb2*64 + ((u ^ (rb2&7))<<3)]);
      }
      #pragma unroll
      for (int fi = 0; fi < 4; fi++)
        #pragma unroll
        for (int fj = 0; fj < 4; fj++)
          acc[fi][fj] = __builtin_amdgcn_mfma_f32_16x16x32_bf16(af[fi], bfr[fj], acc[fi][fj], 0, 0, 0);
    }
    __syncthreads();
  }
  float* dst = pp + ((size_t)kc*8 + b)*128*256;
  #pragma unroll
  for (int fj = 0; fj < 4; fj++){
    int col = nt*128 + wc*64 + fj*16 + lr;
    #pragma unroll
    for (int fi = 0; fi < 4; fi++){
      int rb = wr*64 + fi*16 + lk*4;
      #pragma unroll
      for (int r = 0; r < 4; r++)
        dst[(size_t)(rb + r)*256 + col] = acc[fi][fj][r];
    }
  }
}

// ---------------- reduce split-K partials ----------------
__global__ __launch_bounds__(256) void k_pool2b(const float* __restrict__ pp,
                                                unsigned short* __restrict__ pool_bf_s){
  int bk = blockIdx.x, side = blockIdx.y, c = threadIdx.x;
  int b = bk >> 6, k = bk & 63;
  float s = 0.f;
  #pragma unroll
  for (int kc = 0; kc < 8; kc++)
    s += pp[(((size_t)kc*8 + b)*128 + side*64 + k)*256 + c];
  pool_bf_s[((size_t)side*512 + bk)*256 + c] = f2b(s);
}

// ---------------- MFMA attention (both sides, grid 1024) ----------------
__global__ __launch_bounds__(256) void k_attn2(
    const unsigned short* __restrict__ qq2, const unsigned short* __restrict__ kk2,
    const unsigned short* __restrict__ vvT2, unsigned short* __restrict__ obf2){
  __shared__ unsigned short sk[64*256];
  __shared__ unsigned short svT[256*64];
  __shared__ unsigned short sp[4][16*64];
  __shared__ unsigned short sow[4][16*32];
  int tid = threadIdx.x, w = tid >> 6, l = tid & 63;
  int blk = blockIdx.x;
  int side = (blk >= 512) ? 1 : 0;
  int lblk = blk - side*512;
  int b = lblk >> 6;
  int l15 = l & 15, lg = l >> 4;
  const uint4* ksrc = (const uint4*)(kk2 + ((size_t)side*512 + (size_t)b*64)*256);
  #pragma unroll
  for (int i = 0; i < 8; i++){
    int u = i*256 + tid;
    int row = u >> 5, j = u & 31;
    *(uint4*)&sk[row*256 + ((j ^ (row&7))<<3)] = ksrc[u];
  }
  const uint4* vsrc = (const uint4*)(vvT2 + ((size_t)side*B_ + b)*256*64);
  #pragma unroll
  for (int i = 0; i < 8; i++){
    int u = i*256 + tid;
    int row = u >> 3, j = u & 7;
    *(uint4*)&svT[row*64 + ((j ^ (row&7))<<3)] = vsrc[u];
  }
  __syncthreads();
  size_t qrow = (size_t)blk*64 + w*16 + l15;
  for (int h = 0; h < 8; h++){
    v8bf aq = *(const v8bf*)(qq2 + qrow*256 + h*32 + lg*8);
    f32x4 s[4];
    #pragma unroll
    for (int kt = 0; kt < 4; kt++){
      int row = kt*16 + l15;
      v8bf bk = *(const v8bf*)&sk[row*256 + (((h*4 + lg) ^ (row&7))<<3)];
      f32x4 z = {};
      s[kt] = __builtin_amdgcn_mfma_f32_16x16x32_bf16(aq, bk, z, 0, 0, 0);
    }
    #pragma unroll
    for (int r = 0; r < 4; r++){
      float v0 = s[0][r]*SCALE_, v1 = s[1][r]*SCALE_;
      float v2 = s[2][r]*SCALE_, v3 = s[3][r]*SCALE_;
      float mx = fmaxf(fmaxf(v0, v1), fmaxf(v2, v3));
      mx = fmaxf(mx, __shfl_xor(mx, 1));
      mx = fmaxf(mx, __shfl_xor(mx, 2));
      mx = fmaxf(mx, __shfl_xor(mx, 4));
      mx = fmaxf(mx, __shfl_xor(mx, 8));
      float e0 = __expf(v0-mx), e1 = __expf(v1-mx);
      float e2 = __expf(v2-mx), e3 = __expf(v3-mx);
      float sum = e0+e1+e2+e3;
      sum += __shfl_xor(sum, 1); sum += __shfl_xor(sum, 2);
      sum += __shfl_xor(sum, 4); sum += __shfl_xor(sum, 8);
      float inv = 1.0f/sum;
      s[0][r] = e0*inv; s[1][r] = e1*inv; s[2][r] = e2*inv; s[3][r] = e3*inv;
    }
    #pragma unroll
    for (int kt = 0; kt < 4; kt++){
      int colu = kt*2 + (l15>>3);
      #pragma unroll
      for (int r = 0; r < 4; r++){
        int row = lg*4 + r;
        sp[w][row*64 + ((colu ^ (row&7))<<3) + (l&7)] = f2b(s[kt][r]);
      }
    }
    f32x4 o[2] = {};
    #pragma unroll
    for (int k2 = 0; k2 < 2; k2++){
      v8bf pa = *(const v8bf*)&sp[w][l15*64 + (((k2*4 + lg) ^ (l15&7))<<3)];
      #pragma unroll
      for (int dt = 0; dt < 2; dt++){
        int vrow = h*32 + dt*16 + l15;
        v8bf bv = *(const v8bf*)&svT[vrow*64 + (((k2*4 + lg) ^ (vrow&7))<<3)];
        o[dt] = __builtin_amdgcn_mfma_f32_16x16x32_bf16(pa, bv, o[dt], 0, 0, 0);
      }
    }
    #pragma unroll
    for (int dt = 0; dt < 2; dt++)
      #pragma unroll
      for (int r = 0; r < 4; r++)
        sow[w][(lg*4 + r)*32 + dt*16 + l15] = f2b(o[dt][r]);
    uint4 ov = *(const uint4*)&sow[w][l15*32 + lg*8];
    *(uint4*)(obf2 + qrow*256 + h*32 + lg*8) = ov;
  }
}

// ---------------- residual + LayerNorm (n2, both sides) ----------------
__global__ __launch_bounds__(256) void k_ln2(
    const unsigned short* __restrict__ resid, const unsigned short* __restrict__ delta,
    const float* __restrict__ n2g, const float* __restrict__ n2b, int sl0,
    unsigned short* __restrict__ qout){
  int wv = threadIdx.x >> 6, l = threadIdx.x & 63;
  size_t m = (size_t)blockIdx.x*4 + wv;
  int side = (m >= (size_t)M_) ? 1 : 0;
  const float* g = n2g + (size_t)(sl0 + side*L_)*C_;
  const float* bta = n2b + (size_t)(sl0 + side*L_)*C_;
  uint2 dv = *(const uint2*)(delta + m*256 + l*4);
  float d0 = b2f((unsigned short)(dv.x & 0xffff)), d1 = b2f((unsigned short)(dv.x >> 16));
  float d2 = b2f((unsigned short)(dv.y & 0xffff)), d3 = b2f((unsigned short)(dv.y >> 16));
  uint2 rv = *(const uint2*)(resid + m*256 + l*4);
  float x0 = b2f((unsigned short)(rv.x & 0xffff)) + d0;
  float x1 = b2f((unsigned short)(rv.x >> 16)) + d1;
  float x2 = b2f((unsigned short)(rv.y & 0xffff)) + d2;
  float x3 = b2f((unsigned short)(rv.y >> 16)) + d3;
  float s = x0+x1+x2+x3;
  float ss = x0*x0+x1*x1+x2*x2+x3*x3;
  #pragma unroll
  for (int off = 32; off; off >>= 1){
    s  += __shfl_xor(s, off);
    ss += __shfl_xor(ss, off);
  }
  float mean = s * (1.0f/256.0f);
  float var = ss * (1.0f/256.0f) - mean*mean;
  float rstd = 1.0f / sqrtf(var + 1e-5f);
  float4 gv = *(const float4*)(g + l*4);
  float4 bv = *(const float4*)(bta + l*4);
  float y0 = (x0-mean)*rstd*gv.x + bv.x;
  float y1 = (x1-mean)*rstd*gv.y + bv.y;
  float y2 = (x2-mean)*rstd*gv.z + bv.z;
  float y3 = (x3-mean)*rstd*gv.w + bv.w;
  uint32_t p0 = (uint32_t)f2b(y0) | ((uint32_t)f2b(y1)<<16);
  uint32_t p1 = (uint32_t)f2b(y2) | ((uint32_t)f2b(y3)<<16);
  *(uint2*)(qout + m*256 + l*4) = make_uint2(p0,p1);
}

// ---------------- final select + transpose ----------------
__global__ __launch_bounds__(256) void k_select(
    const unsigned short* __restrict__ qA, const unsigned short* __restrict__ qB,
    const float* __restrict__ featT, const float* __restrict__ heat,
    const int* __restrict__ counts, float* __restrict__ out){
  __shared__ float t[32][33];
  int b = blockIdx.z;
  int n0 = blockIdx.x*32, c0 = blockIdx.y*32;
  int tx = threadIdx.x, ty = threadIdx.y;
  bool valid = (counts[b*2] > 0) && (counts[b*2+1] > 0);
  #pragma unroll
  for (int i = 0; i < 4; i++){
    int nl = ty*4+i;
    size_t m = (size_t)b*4096 + n0 + nl;
    float v;
    if (!valid) v = featT[m*256 + c0 + tx];
    else {
      bool fg = heat[(size_t)b*4096 + n0 + nl] >= 0.5f;
      v = fg ? b2f(qA[m*256 + c0 + tx]) : b2f(qB[m*256 + c0 + tx]);
    }
    t[nl][tx] = v;
  }
  __syncthreads();
  #pragma unroll
  for (int i = 0; i < 4; i++){
    int cl = ty*4+i;
    out[((size_t)b*256 + c0 + cl)*4096 + n0 + tx] = t[tx][cl];
  }
}

extern "C" void kernel_launch(void* const* d_in, const int* in_sizes, int n_in,
                              void* d_out, int out_size, void* d_ws, size_t ws_size,
                              hipStream_t stream){
  const float* x         = (const float*)d_in[0];
  const float* y         = (const float*)d_in[1];
  const float* proj_w    = (const float*)d_in[2];
  const float* proj_b    = (const float*)d_in[3];
  const float* sal_w     = (const float*)d_in[4];
  const float* sal_b     = (const float*)d_in[5];
  const float* soft_w    = (const float*)d_in[6];
  const float* soft_b    = (const float*)d_in[7];
  const float* attn_in_w = (const float*)d_in[8];
  const float* attn_in_b = (const float*)d_in[9];
  const float* attn_out_w= (const float*)d_in[10];
  const float* attn_out_b= (const float*)d_in[11];
  const float* n1_g      = (const float*)d_in[12];
  const float* n1_b      = (const float*)d_in[13];
  const float* ffn_w1    = (const float*)d_in[14];
  const float* ffn_b1    = (const float*)d_in[15];
  const float* ffn_w2    = (const float*)d_in[16];
  const float* ffn_b2    = (const float*)d_in[17];
  const float* n2_g      = (const float*)d_in[18];
  const float* n2_b      = (const float*)d_in[19];
  float* out = (float*)d_out;

  char* p = (char*)d_ws;
  auto alloc = [&](size_t bytes){ char* r = p; p += (bytes + 255) & ~(size_t)255; return r; };
  unsigned short* big0 = (unsigned short*)alloc((size_t)M2_*C_*2);
  unsigned short* xcT  = big0;
  unsigned short* qq2  = big0;
  float* featT = (float*)alloc((size_t)M_*C_*4);
  unsigned short* q2   = (unsigned short*)alloc((size_t)M2_*C_*2);
  unsigned short* swh  = q2;
  unsigned short* obf2 = (unsigned short*)alloc((size_t)M2_*C_*2);
  unsigned short* featC = obf2;
  unsigned short* featbf = (unsigned short*)alloc((size_t)M_*C_*2);
  unsigned short* tmpb2 = (unsigned short*)alloc((size_t)M2_*C_*2);
  float* g_all = (float*)tmpb2;
  float* pp    = (float*)alloc((size_t)8*8*128*256*4);
  double* salp = (double*)pp;
  unsigned short* pool_bf_s = (unsigned short*)alloc((size_t)2*512*256*2);
  unsigned short* kk2  = (unsigned short*)alloc((size_t)2*B_*K_*C_*2);
  unsigned short* vvT2 = (unsigned short*)alloc((size_t)2*B_*C_*K_*2);
  float* heat = (float*)alloc((size_t)B_*N_*4);
  double* u   = (double*)alloc(513*8);
  int* counts = (int*)alloc(64);
  float* zbias = (float*)alloc(512);
  unsigned short* projw_bf = (unsigned short*)alloc((size_t)C_*512*2);
  unsigned short* aiw_bf = (unsigned short*)alloc((size_t)2*L_*768*C_*2);
  unsigned short* f1w_bf = (unsigned short*)alloc((size_t)2*L_*FF_*C_*2);
  unsigned short* f2w_bf = (unsigned short*)alloc((size_t)2*L_*C_*FF_*2);
  unsigned short* aow_bf = (unsigned short*)alloc((size_t)2*L_*C_*C_*2);
  unsigned short* sw2_bf = (unsigned short*)alloc((size_t)2*K_*C_*2);

  hipMemsetAsync(counts, 0, 64, stream);
  hipMemsetAsync(zbias, 0, 512, stream);
  k_compute_u<<<1, 512, 0, stream>>>(sal_w, proj_w, proj_b, sal_b, u);
  k_sal_part<<<dim3(128, 16), 256, 0, stream>>>(x, y, u, salp);
  k_sal_red<<<128, 256, 0, stream>>>(salp, u, heat, counts);

  {
    int n0c = (int)((size_t)2*L_*FF_*C_);
    k_convall<<<dim3((unsigned)((n0c/4 + 255)/256), 6), 256, 0, stream>>>(
        ffn_w1, f1w_bf, n0c,
        ffn_w2, f2w_bf, (int)((size_t)2*L_*C_*FF_),
        attn_in_w, aiw_bf, (int)((size_t)2*L_*768*C_),
        attn_out_w, aow_bf, (int)((size_t)2*L_*C_*C_),
        proj_w, projw_bf, (int)((size_t)C_*512),
        soft_w, sw2_bf, (int)((size_t)2*K_*C_));
  }

  k_build_xcT<<<dim3(N_/32, 512/32, B_), dim3(32,8), 0, stream>>>(x, y, xcT);
  k_gemm_bt<0><<<dim3(M_/128, C_/128), 256, 0, stream>>>(xcT, projw_bf, proj_b, featT, M_, C_, 512);
  k_featmir<<<dim3(N_/32, C_/32, B_), dim3(32,8), 0, stream>>>(featT, featbf, featC);

  k_gemm_bt<0><<<dim3(M_/128, 1), 256, 0, stream>>>(featbf, sw2_bf, zbias, g_all, M_, 128, C_);
  k_swh<<<M_/64, 256, 0, stream>>>(g_all, heat, soft_b, swh);
  k_poolgemm<<<dim3(8, 2, B_), 256, 0, stream>>>(swh, featC, pp);
  k_pool2b<<<dim3(512, 2), 256, 0, stream>>>(pp, pool_bf_s);

  for (int lyr = 0; lyr < L_; ++lyr){
    const unsigned short* qin0 = (lyr == 0) ? featbf : q2;
    const unsigned short* qin1 = (lyr == 0) ? featbf : (q2 + (size_t)M_*C_);
    k_qkv<<<dim3(528, 2), 256, 0, stream>>>(qin0, qin1, pool_bf_s, aiw_bf, attn_in_b, lyr,
                                            qq2, kk2, vvT2);
    k_attn2<<<1024, 256, 0, stream>>>(qq2, kk2, vvT2, obf2);
    if (lyr == 0)
      k_gemm_ln<1><<<512, 512, 0, stream>>>(obf2, aow_bf, attn_out_b, featT, n1_g, n1_b, lyr, q2);
    else
      k_gemm_ln<0><<<512, 512, 0, stream>>>(obf2, aow_bf, attn_out_b, q2, n1_g, n1_b, lyr, q2);
    k_ffn<<<512, 512, 0, stream>>>(q2, f1w_bf, ffn_b1, f2w_bf, ffn_b2, lyr, tmpb2);
    k_ln2<<<M2_/4, 256, 0, stream>>>(q2, tmpb2, n2_g, n2_b, lyr, q2);
  }
  k_select<<<dim3(N_/32, C_/32, B_), dim3(32,8), 0, stream>>>(q2, q2 + (size_t)M_*C_, featT, heat, counts, out);
}

// Round 18
// 783.450 us; speedup vs baseline: 1.0083x; 1.0083x over previous
//
#include <hip/hip_runtime.h>
#include <stdint.h>

#define B_ 8
#define C_ 256
#define N_ 4096
#define K_ 64
#define NH_ 8
#define FF_ 1024
#define L_ 3
#define M_ (B_*N_)
#define M2_ (2*M_)
#define SCALE_ 0.17677669529663687f

typedef float f32x4 __attribute__((ext_vector_type(4)));
typedef __bf16 v8bf __attribute__((ext_vector_type(8)));

__device__ __forceinline__ float b2f(unsigned short h){
  union { uint32_t u; float f; } v; v.u = ((uint32_t)h) << 16; return v.f;
}
__device__ __forceinline__ unsigned short f2b(float f){
  union { float f; uint32_t u; } v; v.f = f;
  uint32_t r = v.u + 0x7fffu + ((v.u >> 16) & 1u);
  return (unsigned short)(r >> 16);
}
__device__ __forceinline__ void gload_lds16(const void* g, void* l){
  __builtin_amdgcn_global_load_lds(
      (const __attribute__((address_space(1))) unsigned int*)g,
      (__attribute__((address_space(3))) unsigned int*)l, 16, 0, 0);
}
__device__ __forceinline__ void unpack8(uint4 v, float* o){
  o[0]=b2f((unsigned short)(v.x & 0xffff)); o[1]=b2f((unsigned short)(v.x >> 16));
  o[2]=b2f((unsigned short)(v.y & 0xffff)); o[3]=b2f((unsigned short)(v.y >> 16));
  o[4]=b2f((unsigned short)(v.z & 0xffff)); o[5]=b2f((unsigned short)(v.z >> 16));
  o[6]=b2f((unsigned short)(v.w & 0xffff)); o[7]=b2f((unsigned short)(v.w >> 16));
}

// ---------------- all weight conversions in one dispatch ----------------
__global__ __launch_bounds__(256) void k_convall(
    const float* s0, unsigned short* d0, int n0_,
    const float* s1, unsigned short* d1, int n1_,
    const float* s2, unsigned short* d2, int n2_,
    const float* s3, unsigned short* d3, int n3_,
    const float* s4, unsigned short* d4, int n4_,
    const float* s5, unsigned short* d5, int n5_){
  const float* s; unsigned short* d; int n;
  switch (blockIdx.y){
    case 0: s=s0; d=d0; n=n0_; break;
    case 1: s=s1; d=d1; n=n1_; break;
    case 2: s=s2; d=d2; n=n2_; break;
    case 3: s=s3; d=d3; n=n3_; break;
    case 4: s=s4; d=d4; n=n4_; break;
    default:s=s5; d=d5; n=n5_; break;
  }
  int i4 = (blockIdx.x*256 + threadIdx.x)*4;
  if (i4 >= n) return;
  float4 v = *(const float4*)(s + i4);
  uint32_t p0 = (uint32_t)f2b(v.x) | ((uint32_t)f2b(v.y) << 16);
  uint32_t p1 = (uint32_t)f2b(v.z) | ((uint32_t)f2b(v.w) << 16);
  *(uint2*)(d + i4) = make_uint2(p0, p1);
}

// ---------------- build xcT ----------------
__global__ __launch_bounds__(256) void k_build_xcT(const float* __restrict__ x,
                                                   const float* __restrict__ y,
                                                   unsigned short* __restrict__ xcT){
  __shared__ float t[32][33];
  int b = blockIdx.z;
  int n0 = blockIdx.x*32, c0 = blockIdx.y*32;
  int tx = threadIdx.x, ty = threadIdx.y;
  const float* src = (c0 < 256) ? (x + ((size_t)b*256 + c0)*N_)
                                : (y + ((size_t)b*256 + (c0-256))*N_);
  #pragma unroll
  for (int i = 0; i < 4; i++){
    int cl = ty*4 + i;
    t[cl][tx] = src[(size_t)cl*N_ + n0 + tx];
  }
  __syncthreads();
  #pragma unroll
  for (int i = 0; i < 4; i++){
    int nl = ty*4 + i;
    xcT[((size_t)b*N_ + n0 + nl)*512 + c0 + tx] = f2b(t[tx][nl]);
  }
}

// ---------------- feat mirrors ----------------
__global__ __launch_bounds__(256) void k_featmir(const float* __restrict__ featT,
                                                 unsigned short* __restrict__ featbf,
                                                 unsigned short* __restrict__ featC){
  __shared__ float t[32][33];
  int b = blockIdx.z;
  int n0 = blockIdx.x*32, c0 = blockIdx.y*32;
  int tx = threadIdx.x, ty = threadIdx.y;
  #pragma unroll
  for (int i = 0; i < 4; i++){
    int nl = ty*4 + i;
    size_t m = (size_t)b*N_ + n0 + nl;
    float v = featT[m*256 + c0 + tx];
    t[nl][tx] = v;
    featbf[m*256 + c0 + tx] = f2b(v);
  }
  __syncthreads();
  #pragma unroll
  for (int i = 0; i < 4; i++){
    int cl = ty*4 + i;
    featC[((size_t)b*256 + c0 + cl)*(size_t)N_ + n0 + tx] = f2b(t[tx][cl]);
  }
}

// ---------------- combined saliency vector (fp64) ----------------
__global__ __launch_bounds__(512) void k_compute_u(const float* __restrict__ sal_w,
                                                   const float* __restrict__ proj_w,
                                                   const float* __restrict__ proj_b,
                                                   const float* __restrict__ sal_b,
                                                   double* __restrict__ u){
  int c2 = threadIdx.x;
  double acc = 0.0;
  for (int c = 0; c < 256; ++c)
    acc += (double)sal_w[c] * (double)proj_w[(size_t)c*512 + c2];
  u[c2] = acc;
  if (c2 == 0){
    double s0 = (double)sal_b[0];
    for (int c = 0; c < 256; ++c) s0 += (double)sal_w[c] * (double)proj_b[c];
    u[512] = s0;
  }
}

// ---------------- sal partials ----------------
__global__ __launch_bounds__(256) void k_sal_part(const float* __restrict__ x,
                                                  const float* __restrict__ y,
                                                  const double* __restrict__ u,
                                                  double* __restrict__ part){
  int pix = blockIdx.x*256 + threadIdx.x;
  int cc = blockIdx.y;
  int b = pix >> 12, n = pix & 4095;
  int c0 = cc*32;
  const float* src = (c0 < 256) ? (x + ((size_t)b*256 + c0)*N_ + n)
                                : (y + ((size_t)b*256 + (c0-256))*N_ + n);
  const double* uu = u + c0;
  double acc = 0.0;
  #pragma unroll 8
  for (int c = 0; c < 32; ++c) acc += uu[c] * (double)src[(size_t)c*N_];
  part[(size_t)cc*32768 + pix] = acc;
}

// ---------------- sal reduce ----------------
__global__ __launch_bounds__(256) void k_sal_red(const double* __restrict__ part,
                                                 const double* __restrict__ u,
                                                 float* __restrict__ heat,
                                                 int* __restrict__ counts){
  int pix = blockIdx.x*256 + threadIdx.x;
  int b = pix >> 12;
  double acc = u[512];
  #pragma unroll
  for (int cc = 0; cc < 16; cc++) acc += part[(size_t)cc*32768 + pix];
  float hf = (float)(1.0 / (1.0 + exp(-acc)));
  heat[pix] = hf;
  unsigned long long mfg = __ballot(hf >= 0.5f);
  unsigned long long mbg = __ballot(hf < 0.5f);
  if ((threadIdx.x & 63) == 0){
    atomicAdd(&counts[b*2+0], (int)__popcll(mfg));
    atomicAdd(&counts[b*2+1], (int)__popcll(mbg));
  }
}

// ---------------- bf16 MFMA GEMM (2-phase dbuf, XOR swizzle) ----------------
template<int EPI>
__global__ __launch_bounds__(256) void k_gemm_bt(
    const unsigned short* __restrict__ A, const unsigned short* __restrict__ W,
    const float* __restrict__ bias, void* __restrict__ out,
    int M, int N, int K){
  __shared__ unsigned short smem[2][2][128*64];
  int tid = threadIdx.x;
  int w = tid >> 6, l = tid & 63;
  int m0 = blockIdx.x * 128, n0 = blockIdx.y * 128;
  int wr = w >> 1, wc = w & 1;
  int lr = l & 15, lk = l >> 4;
  f32x4 acc[4][4] = {};
  int nt = K >> 6;
  #pragma unroll
  for (int i = 0; i < 4; i++){
    int idx = i*256 + tid;
    int row = idx >> 3, su = ((idx & 7) ^ (row & 7))*8;
    gload_lds16(A + (size_t)(m0+row)*K + su, &smem[0][0][idx*8]);
    gload_lds16(W + (size_t)(n0+row)*K + su, &smem[0][1][idx*8]);
  }
  __syncthreads();
  for (int t = 0; t < nt; ++t){
    int cur = t & 1;
    if (t + 1 < nt){
      int k0 = (t + 1) << 6;
      #pragma unroll
      for (int i = 0; i < 4; i++){
        int idx = i*256 + tid;
        int row = idx >> 3, su = ((idx & 7) ^ (row & 7))*8;
        gload_lds16(A + (size_t)(m0+row)*K + k0 + su, &smem[cur^1][0][idx*8]);
        gload_lds16(W + (size_t)(n0+row)*K + k0 + su, &smem[cur^1][1][idx*8]);
      }
    }
    const unsigned short* ldsA = smem[cur][0];
    const unsigned short* ldsB = smem[cur][1];
    #pragma unroll
    for (int kk = 0; kk < 2; kk++){
      v8bf af[4], bfr[4];
      #pragma unroll
      for (int f = 0; f < 4; f++){
        int ra = wr*64 + f*16 + lr;
        int rb2 = wc*64 + f*16 + lr;
        int u = kk*4 + lk;
        af[f]  = *(const v8bf*)(&ldsA[ra*64 + ((u ^ (ra&7))<<3)]);
        bfr[f] = *(const v8bf*)(&ldsB[rb2*64 + ((u ^ (rb2&7))<<3)]);
      }
      #pragma unroll
      for (int fi = 0; fi < 4; fi++)
        #pragma unroll
        for (int fj = 0; fj < 4; fj++)
          acc[fi][fj] = __builtin_amdgcn_mfma_f32_16x16x32_bf16(af[fi], bfr[fj], acc[fi][fj], 0, 0, 0);
    }
    __syncthreads();
  }
  if (EPI == 1 || EPI == 2){
    unsigned short* st = &smem[0][0][0];
    #pragma unroll
    for (int fj = 0; fj < 4; fj++){
      int col = wc*64 + fj*16 + lr;
      float bv = bias[n0 + col];
      #pragma unroll
      for (int fi = 0; fi < 4; fi++){
        int rl = wr*64 + fi*16 + lk*4;
        #pragma unroll
        for (int r = 0; r < 4; r++){
          float v = acc[fi][fj][r] + bv;
          if (EPI == 1) v = fmaxf(v, 0.f);
          st[(rl + r)*136 + col] = f2b(v);
        }
      }
    }
    __syncthreads();
    #pragma unroll
    for (int it = 0; it < 8; it++){
      int idx = it*256 + tid;
      int row = idx >> 4, c8 = (idx & 15)*8;
      *(uint4*)((unsigned short*)out + (size_t)(m0+row)*N + n0 + c8)
          = *(const uint4*)&st[row*136 + c8];
    }
  } else {
    #pragma unroll
    for (int fj = 0; fj < 4; fj++){
      int col = n0 + wc*64 + fj*16 + lr;
      float bv = bias[col];
      #pragma unroll
      for (int fi = 0; fi < 4; fi++){
        int rb = m0 + wr*64 + fi*16 + lk*4;
        #pragma unroll
        for (int r = 0; r < 4; r++){
          float v = acc[fi][fj][r] + bv;
          ((float*)out)[(size_t)(rb + r)*N + col] = v;
        }
      }
    }
  }
}

// ---------------- merged QKV projection (both sides), one dispatch ----------------
__global__ __launch_bounds__(256) void k_qkv(
    const unsigned short* __restrict__ qin0, const unsigned short* __restrict__ qin1,
    const unsigned short* __restrict__ pool2, const unsigned short* __restrict__ aiw,
    const float* __restrict__ aib, int sl0,
    unsigned short* __restrict__ qq2, unsigned short* __restrict__ kk2,
    unsigned short* __restrict__ vvT2){
  __shared__ unsigned short smem[2][2][128*64];
  int tid = threadIdx.x;
  int w = tid >> 6, l = tid & 63;
  int bx = blockIdx.x, n0 = blockIdx.y*128;
  int wr = w >> 1, wc = w & 1;
  int lr = l & 15, lk = l >> 4;
  const unsigned short* Aptr; size_t abase;
  const unsigned short* W; const float* bias;
  int mode, m0;
  if (bx < 512){
    mode = 0; m0 = bx*128;
    int side = (m0 >= M_) ? 1 : 0;
    Aptr = side ? qin1 : qin0; abase = (size_t)(m0 - side*M_);
    int sl = sl0 + side*L_;
    W = aiw + (size_t)sl*768*C_;
    bias = aib + (size_t)sl*768;
  } else if (bx < 520){
    mode = 1; m0 = (bx - 512)*128;
    int side = (m0 >= 512) ? 1 : 0;
    Aptr = pool2; abase = (size_t)m0;
    int sl = sl0 + side*L_;
    W = aiw + (size_t)sl*768*C_ + (size_t)256*C_;
    bias = aib + (size_t)sl*768 + 256;
  } else {
    mode = 2; m0 = (bx - 520)*128;
    int side = (m0 >= 512) ? 1 : 0;
    Aptr = pool2; abase = (size_t)m0;
    int sl = sl0 + side*L_;
    W = aiw + (size_t)sl*768*C_ + (size_t)512*C_;
    bias = aib + (size_t)sl*768 + 512;
  }
  f32x4 acc[4][4] = {};
  #pragma unroll
  for (int i = 0; i < 4; i++){
    int idx = i*256 + tid;
    int row = idx >> 3, su = ((idx & 7) ^ (row & 7))*8;
    gload_lds16(Aptr + (abase+row)*256 + su, &smem[0][0][idx*8]);
    gload_lds16(W + (size_t)(n0+row)*256 + su, &smem[0][1][idx*8]);
  }
  __syncthreads();
  for (int t = 0; t < 4; ++t){
    int cur = t & 1;
    if (t + 1 < 4){
      int k0 = (t + 1) << 6;
      #pragma unroll
      for (int i = 0; i < 4; i++){
        int idx = i*256 + tid;
        int row = idx >> 3, su = ((idx & 7) ^ (row & 7))*8;
        gload_lds16(Aptr + (abase+row)*256 + k0 + su, &smem[cur^1][0][idx*8]);
        gload_lds16(W + (size_t)(n0+row)*256 + k0 + su, &smem[cur^1][1][idx*8]);
      }
    }
    const unsigned short* ldsA = smem[cur][0];
    const unsigned short* ldsB = smem[cur][1];
    #pragma unroll
    for (int kk = 0; kk < 2; kk++){
      v8bf af[4], bfr[4];
      #pragma unroll
      for (int f = 0; f < 4; f++){
        int ra = wr*64 + f*16 + lr;
        int rb2 = wc*64 + f*16 + lr;
        int u = kk*4 + lk;
        af[f]  = *(const v8bf*)(&ldsA[ra*64 + ((u ^ (ra&7))<<3)]);
        bfr[f] = *(const v8bf*)(&ldsB[rb2*64 + ((u ^ (rb2&7))<<3)]);
      }
      #pragma unroll
      for (int fi = 0; fi < 4; fi++)
        #pragma unroll
        for (int fj = 0; fj < 4; fj++)
          acc[fi][fj] = __builtin_amdgcn_mfma_f32_16x16x32_bf16(af[fi], bfr[fj], acc[fi][fj], 0, 0, 0);
    }
    __syncthreads();
  }
  if (mode == 2){
    int side = (m0 >= 512) ? 1 : 0;
    #pragma unroll
    for (int fj = 0; fj < 4; fj++){
      int col = n0 + wc*64 + fj*16 + lr;
      float bv = bias[col];
      #pragma unroll
      for (int fi = 0; fi < 4; fi++){
        int rb = m0 + wr*64 + fi*16 + lk*4;
        #pragma unroll
        for (int r = 0; r < 4; r++){
          float v = acc[fi][fj][r] + bv;
          int rl = rb + r - side*512;
          vvT2[(size_t)side*(B_*C_*K_) + ((size_t)(rl>>6)*256 + col)*64 + (rl&63)] = f2b(v);
        }
      }
    }
  } else {
    unsigned short* outp = (mode == 0) ? qq2 : kk2;
    unsigned short* st = &smem[0][0][0];
    #pragma unroll
    for (int fj = 0; fj < 4; fj++){
      int col = wc*64 + fj*16 + lr;
      float bv = bias[n0 + col];
      #pragma unroll
      for (int fi = 0; fi < 4; fi++){
        int rl = wr*64 + fi*16 + lk*4;
        #pragma unroll
        for (int r = 0; r < 4; r++)
          st[(rl + r)*136 + col] = f2b(acc[fi][fj][r] + bv);
      }
    }
    __syncthreads();
    #pragma unroll
    for (int it = 0; it < 8; it++){
      int idx = it*256 + tid;
      int row = idx >> 4, c8 = (idx & 15)*8;
      *(uint4*)(outp + (size_t)(m0+row)*256 + n0 + c8) = *(const uint4*)&st[row*136 + c8];
    }
  }
}

// ---------------- attn-out GEMM + residual + LayerNorm1 fused (both sides) ----------------
template<int RF32>
__global__ __launch_bounds__(512) void k_gemm_ln(
    const unsigned short* __restrict__ A, const unsigned short* __restrict__ aow,
    const float* __restrict__ aob, const void* __restrict__ resid,
    const float* __restrict__ n1g, const float* __restrict__ n1b, int sl0,
    unsigned short* __restrict__ qout){
  __shared__ unsigned short smem[49152];
  int tid = threadIdx.x;
  int w = tid >> 6, l = tid & 63;
  int m0 = blockIdx.x * 128;
  int side = (m0 >= M_) ? 1 : 0;
  int sl = sl0 + side*L_;
  const unsigned short* W = aow + (size_t)sl*C_*C_;
  const float* bias = aob + (size_t)sl*C_;
  const float* g = n1g + (size_t)sl*C_;
  const float* bta = n1b + (size_t)sl*C_;
  size_t rbase = RF32 ? (size_t)(m0 - side*M_) : (size_t)m0;
  int wm = w >> 2, wf = w & 3;
  int lr = l & 15, lk = l >> 4;
  f32x4 acc[4][4] = {};
  #pragma unroll
  for (int i = 0; i < 2; i++){
    int idx = i*512 + tid;
    int row = idx >> 3, su = ((idx & 7) ^ (row & 7))*8;
    gload_lds16(A + (size_t)(m0+row)*256 + su, &smem[idx*8]);
  }
  #pragma unroll
  for (int i = 0; i < 4; i++){
    int idx = i*512 + tid;
    int row = idx >> 3, su = ((idx & 7) ^ (row & 7))*8;
    gload_lds16(W + (size_t)row*256 + su, &smem[8192 + idx*8]);
  }
  __syncthreads();
  for (int t = 0; t < 4; ++t){
    int cur = t & 1;
    if (t + 1 < 4){
      int k0 = (t + 1) << 6;
      unsigned short* bA = smem + (cur^1)*24576;
      unsigned short* bB = bA + 8192;
      #pragma unroll
      for (int i = 0; i < 2; i++){
        int idx = i*512 + tid;
        int row = idx >> 3, su = ((idx & 7) ^ (row & 7))*8;
        gload_lds16(A + (size_t)(m0+row)*256 + k0 + su, &bA[idx*8]);
      }
      #pragma unroll
      for (int i = 0; i < 4; i++){
        int idx = i*512 + tid;
        int row = idx >> 3, su = ((idx & 7) ^ (row & 7))*8;
        gload_lds16(W + (size_t)row*256 + k0 + su, &bB[idx*8]);
      }
    }
    const unsigned short* bA = smem + cur*24576;
    const unsigned short* bB = bA + 8192;
    #pragma unroll
    for (int kk = 0; kk < 2; kk++){
      v8bf af[4], wb[4];
      int u = kk*4 + lk;
      #pragma unroll
      for (int f = 0; f < 4; f++){
        int ra = wm*64 + f*16 + lr;
        af[f] = *(const v8bf*)&bA[ra*64 + ((u ^ (ra&7))<<3)];
      }
      #pragma unroll
      for (int f = 0; f < 4; f++){
        int rc = wf*64 + f*16 + lr;
        wb[f] = *(const v8bf*)&bB[rc*64 + ((u ^ (rc&7))<<3)];
      }
      #pragma unroll
      for (int fi = 0; fi < 4; fi++)
        #pragma unroll
        for (int fc = 0; fc < 4; fc++)
          acc[fi][fc] = __builtin_amdgcn_mfma_f32_16x16x32_bf16(af[fi], wb[fc], acc[fi][fc], 0, 0, 0);
    }
    __syncthreads();
  }
  unsigned short* st = smem;
  #pragma unroll
  for (int fc = 0; fc < 4; fc++){
    int col = wf*64 + fc*16 + lr;
    float bv = bias[col];
    #pragma unroll
    for (int fi = 0; fi < 4; fi++){
      int rl = wm*64 + fi*16 + lk*4;
      #pragma unroll
      for (int r = 0; r < 4; r++)
        st[(rl + r)*264 + col] = f2b(acc[fi][fc][r] + bv);
    }
  }
  __syncthreads();
  int row = tid >> 2, seg = tid & 3;
  float xv[64];
  #pragma unroll
  for (int j = 0; j < 8; j++){
    int cu = seg*8 + j;
    uint4 dv = *(const uint4*)&st[row*264 + cu*8];
    float dd[8];
    unpack8(dv, dd);
    if (RF32){
      const float* rp = (const float*)resid + (rbase+row)*256 + cu*8;
      float4 r0 = *(const float4*)rp, r1 = *(const float4*)(rp + 4);
      xv[j*8+0] = r0.x + dd[0]; xv[j*8+1] = r0.y + dd[1];
      xv[j*8+2] = r0.z + dd[2]; xv[j*8+3] = r0.w + dd[3];
      xv[j*8+4] = r1.x + dd[4]; xv[j*8+5] = r1.y + dd[5];
      xv[j*8+6] = r1.z + dd[6]; xv[j*8+7] = r1.w + dd[7];
    } else {
      uint4 rv = *(const uint4*)((const unsigned short*)resid + (rbase+row)*256 + cu*8);
      float rr[8];
      unpack8(rv, rr);
      #pragma unroll
      for (int e = 0; e < 8; e++) xv[j*8+e] = rr[e] + dd[e];
    }
  }
  float s = 0.f, q = 0.f;
  #pragma unroll
  for (int i2 = 0; i2 < 64; i2++){ s += xv[i2]; q += xv[i2]*xv[i2]; }
  s += __shfl_xor(s, 1); s += __shfl_xor(s, 2);
  q += __shfl_xor(q, 1); q += __shfl_xor(q, 2);
  float mean = s * (1.0f/256.0f);
  float rstd = 1.0f / sqrtf(q*(1.0f/256.0f) - mean*mean + 1e-5f);
  #pragma unroll
  for (int j = 0; j < 8; j++){
    int c0 = seg*64 + j*8;
    float4 g0 = *(const float4*)(g + c0), g1 = *(const float4*)(g + c0 + 4);
    float4 b0 = *(const float4*)(bta + c0), b1 = *(const float4*)(bta + c0 + 4);
    uint4 ov;
    ov.x = (uint32_t)f2b((xv[j*8+0]-mean)*rstd*g0.x + b0.x)
         | ((uint32_t)f2b((xv[j*8+1]-mean)*rstd*g0.y + b0.y) << 16);
    ov.y = (uint32_t)f2b((xv[j*8+2]-mean)*rstd*g0.z + b0.z)
         | ((uint32_t)f2b((xv[j*8+3]-mean)*rstd*g0.w + b0.w) << 16);
    ov.z = (uint32_t)f2b((xv[j*8+4]-mean)*rstd*g1.x + b1.x)
         | ((uint32_t)f2b((xv[j*8+5]-mean)*rstd*g1.y + b1.y) << 16);
    ov.w = (uint32_t)f2b((xv[j*8+6]-mean)*rstd*g1.z + b1.z)
         | ((uint32_t)f2b((xv[j*8+7]-mean)*rstd*g1.w + b1.w) << 16);
    *(uint4*)&st[row*264 + c0] = ov;
  }
  __syncthreads();
  #pragma unroll
  for (int it = 0; it < 8; it++){
    int idx = it*512 + tid;
    int rw = idx >> 5, c8 = (idx & 31)*8;
    *(uint4*)(qout + (size_t)(m0+rw)*256 + c8) = *(const uint4*)&st[rw*264 + c8];
  }
}

// ---------------- fused FFN v2 (best measured), both sides ----------------
__global__ __launch_bounds__(512) void k_ffn(
    const unsigned short* __restrict__ qb, const unsigned short* __restrict__ f1w,
    const float* __restrict__ f1b, const unsigned short* __restrict__ f2w,
    const float* __restrict__ f2b_, int sl0, unsigned short* __restrict__ outb){
  __shared__ unsigned short smem[73728];
  unsigned short* sA  = smem;
  unsigned short* sW1 = smem + 32768;
  unsigned short* sW2 = smem + 49152;
  unsigned short* sH  = smem + 65536;
  int tid = threadIdx.x;
  int w = tid >> 6, l = tid & 63;
  int m0 = blockIdx.x * 128;
  int side = (m0 >= M_) ? 1 : 0;
  int sl = sl0 + side*L_;
  const unsigned short* W1g = f1w + (size_t)sl*FF_*C_;
  const float* b1g = f1b + (size_t)sl*FF_;
  const unsigned short* W2g = f2w + (size_t)sl*C_*FF_;
  const float* b2g = f2b_ + (size_t)sl*C_;
  int wm = w >> 2, wf = w & 3;
  int lr = l & 15, lk = l >> 4;

  #pragma unroll
  for (int i = 0; i < 8; i++){
    int idx = i*512 + tid;
    int row = idx >> 5, g = idx & 31;
    int su = (g & 24) | ((g & 7) ^ (row & 7));
    gload_lds16(qb + (size_t)(m0+row)*256 + su*8, &sA[idx*8]);
  }
  #pragma unroll
  for (int i = 0; i < 4; i++){
    int idx = i*512 + tid;
    int row = idx >> 5, g = idx & 31;
    int su = (g & 24) | ((g & 7) ^ (row & 7));
    gload_lds16(W1g + (size_t)row*256 + su*8, &sW1[idx*8]);
  }
  #pragma unroll
  for (int i = 0; i < 4; i++){
    int idx = i*512 + tid;
    int row = idx >> 3, g = idx & 7;
    int su = g ^ (row & 7);
    gload_lds16(W2g + (size_t)row*1024 + su*8, &sW2[idx*8]);
  }
  __syncthreads();

  f32x4 acc[4][4] = {};
  for (int cc = 0; cc < 16; ++cc){
    f32x4 hacc[4] = {};
    #pragma unroll
    for (int ks = 0; ks < 8; ks++){
      int g = ks*4 + lk;
      int rf = wf*16 + lr;
      v8bf bf1 = *(const v8bf*)&sW1[rf*256 + (((g & 24) | ((g & 7) ^ (rf & 7)))<<3)];
      #pragma unroll
      for (int f = 0; f < 4; f++){
        int ra = wm*64 + f*16 + lr;
        v8bf af = *(const v8bf*)&sA[ra*256 + (((g & 24) | ((g & 7) ^ (ra & 7)))<<3)];
        hacc[f] = __builtin_amdgcn_mfma_f32_16x16x32_bf16(af, bf1, hacc[f], 0, 0, 0);
      }
    }
    {
      int fc = wf*16 + lr;
      float b1v = b1g[cc*64 + fc];
      #pragma unroll
      for (int fi = 0; fi < 4; fi++){
        int mr0 = wm*64 + fi*16 + lk*4;
        #pragma unroll
        for (int r = 0; r < 4; r++){
          float v = fmaxf(hacc[fi][r] + b1v, 0.f);
          int mr = mr0 + r;
          sH[mr*64 + (((fc >> 3) ^ (mr & 7))<<3) + (fc & 7)] = f2b(v);
        }
      }
    }
    __syncthreads();
    if (cc + 1 < 16){
      int f0n = (cc+1)*64;
      #pragma unroll
      for (int i = 0; i < 4; i++){
        int idx = i*512 + tid;
        int row = idx >> 5, g = idx & 31;
        int su = (g & 24) | ((g & 7) ^ (row & 7));
        gload_lds16(W1g + (size_t)(f0n+row)*256 + su*8, &sW1[idx*8]);
      }
    }
    #pragma unroll
    for (int ks2 = 0; ks2 < 2; ks2++){
      int g = ks2*4 + lk;
      v8bf ha[4], wb[4];
      #pragma unroll
      for (int f = 0; f < 4; f++){
        int rh = wm*64 + f*16 + lr;
        ha[f] = *(const v8bf*)&sH[rh*64 + ((g ^ (rh & 7))<<3)];
      }
      #pragma unroll
      for (int f = 0; f < 4; f++){
        int rc = wf*64 + f*16 + lr;
        wb[f] = *(const v8bf*)&sW2[rc*64 + ((g ^ (rc & 7))<<3)];
      }
      #pragma unroll
      for (int fi = 0; fi < 4; fi++)
        #pragma unroll
        for (int fc = 0; fc < 4; fc++)
          acc[fi][fc] = __builtin_amdgcn_mfma_f32_16x16x32_bf16(ha[fi], wb[fc], acc[fi][fc], 0, 0, 0);
    }
    __syncthreads();
    if (cc + 1 < 16){
      int f0n = (cc+1)*64;
      #pragma unroll
      for (int i = 0; i < 4; i++){
        int idx = i*512 + tid;
        int row = idx >> 3, g = idx & 7;
        int su = g ^ (row & 7);
        gload_lds16(W2g + (size_t)row*1024 + f0n + su*8, &sW2[idx*8]);
      }
    }
  }
  unsigned short* st = smem;
  #pragma unroll
  for (int fc = 0; fc < 4; fc++){
    int col = wf*64 + fc*16 + lr;
    float bv = b2g[col];
    #pragma unroll
    for (int fi = 0; fi < 4; fi++){
      int rl = wm*64 + fi*16 + lk*4;
      #pragma unroll
      for (int r = 0; r < 4; r++)
        st[(rl + r)*264 + col] = f2b(acc[fi][fc][r] + bv);
    }
  }
  __syncthreads();
  #pragma unroll
  for (int it = 0; it < 8; it++){
    int idx = it*512 + tid;
    int row = idx >> 5, c8 = (idx & 31)*8;
    *(uint4*)(outb + (size_t)(m0+row)*256 + c8) = *(const uint4*)&st[row*264 + c8];
  }
}

// ---------------- swh ----------------
__global__ __launch_bounds__(256) void k_swh(const float* __restrict__ g_all,
                                             const float* __restrict__ heat,
                                             const float* __restrict__ soft_b,
                                             unsigned short* __restrict__ swh){
  __shared__ float gl[64*129];
  __shared__ float hml[64];
  int tid = threadIdx.x;
  int blk = blockIdx.x;
  size_t m0 = (size_t)blk*64;
  int b = (int)(m0 >> 12), n0 = (int)(m0 & 4095);
  #pragma unroll
  for (int i = 0; i < 32; i++){
    int idx = i*256 + tid;
    int row = idx >> 7, col = idx & 127;
    gl[row*129 + col] = g_all[(m0 + row)*128 + col];
  }
  if (tid < 64) hml[tid] = heat[(size_t)b*4096 + n0 + tid];
  __syncthreads();
  int k = tid >> 2, j0 = (tid & 3)*16;
  #pragma unroll
  for (int s = 0; s < 2; s++){
    float sb = soft_b[s*64 + k];
    unsigned short vals[16];
    #pragma unroll
    for (int j = 0; j < 16; j++){
      int n = j0 + j;
      float h = hml[n];
      float hm = s ? (1.0f - h) : h;
      vals[j] = f2b((gl[n*129 + s*64 + k]*hm + sb)*hm);
    }
    unsigned short* dst = swh + (((size_t)b*2 + s)*64 + k)*4096 + n0 + j0;
    uint4 o0, o1;
    o0.x = vals[0] | ((uint32_t)vals[1]<<16);  o0.y = vals[2] | ((uint32_t)vals[3]<<16);
    o0.z = vals[4] | ((uint32_t)vals[5]<<16);  o0.w = vals[6] | ((uint32_t)vals[7]<<16);
    o1.x = vals[8] | ((uint32_t)vals[9]<<16);  o1.y = vals[10]| ((uint32_t)vals[11]<<16);
    o1.z = vals[12]| ((uint32_t)vals[13]<<16); o1.w = vals[14]| ((uint32_t)vals[15]<<16);
    *(uint4*)dst = o0;
    *(uint4*)(dst + 8) = o1;
  }
}

// ---------------- pool GEMM (split-K) ----------------
__global__ __launch_bounds__(256) void k_poolgemm(
    const unsigned short* __restrict__ swh, const unsigned short* __restrict__ featC,
    float* __restrict__ pp){
  __shared__ unsigned short ldsA[128*64];
  __shared__ unsigned short ldsB[128*64];
  int tid = threadIdx.x;
  int w = tid >> 6, l = tid & 63;
  int kc = blockIdx.x, nt = blockIdx.y, b = blockIdx.z;
  int wr = w >> 1, wc = w & 1;
  int lr = l & 15, lk = l >> 4;
  const unsigned short* A = swh  + (size_t)b*128*4096 + kc*512;
  const unsigned short* W = featC + ((size_t)b*256 + nt*128)*4096 + kc*512;
  f32x4 acc[4][4] = {};
  for (int k0 = 0; k0 < 512; k0 += 64){
    #pragma unroll
    for (int i = 0; i < 4; i++){
      int idx = i*256 + tid;
      int row = idx >> 3, su = (idx & 7) ^ (row & 7);
      gload_lds16(A + (size_t)row*4096 + k0 + su*8, &ldsA[idx*8]);
    }
    #pragma unroll
    for (int i = 0; i < 4; i++){
      int idx = i*256 + tid;
      int row = idx >> 3, su = (idx & 7) ^ (row & 7);
      gload_lds16(W + (size_t)row*4096 + k0 + su*8, &ldsB[idx*8]);
    }
    __syncthreads();
    #pragma unroll
    for (int kk = 0; kk < 2; kk++){
      v8bf af[4], bfr[4];
      #pragma unroll
      for (int f = 0; f < 4; f++){
        int ra = wr*64 + f*16 + lr;
        int rb2 = wc*64 + f*16 + lr;
        int u = kk*4 + lk;
        af[f]  = *(const v8bf*)(&ldsA[ra*64 + ((u ^ (ra&7))<<3)]);
        bfr[f] = *(const v8bf*)(&ldsB[rb2*64 + ((u ^ (rb2&7))<<3)]);
      }
      #pragma unroll
      for (int fi = 0; fi < 4; fi++)
        #pragma unroll
        for (int fj = 0; fj < 4; fj++)
          acc[fi][fj] = __builtin_amdgcn_mfma_f32_16x16x32_bf16(af[fi], bfr[fj], acc[fi][fj], 0, 0, 0);
    }
    __syncthreads();
  }
  float* dst = pp + ((size_t)kc*8 + b)*128*256;
  #pragma unroll
  for (int fj = 0; fj < 4; fj++){
    int col = nt*128 + wc*64 + fj*16 + lr;
    #pragma unroll
    for (int fi = 0; fi < 4; fi++){
      int rb = wr*64 + fi*16 + lk*4;
      #pragma unroll
      for (int r = 0; r < 4; r++)
        dst[(size_t)(rb + r)*256 + col] = acc[fi][fj][r];
    }
  }
}

// ---------------- reduce split-K partials ----------------
__global__ __launch_bounds__(256) void k_pool2b(const float* __restrict__ pp,
                                                unsigned short* __restrict__ pool_bf_s){
  int bk = blockIdx.x, side = blockIdx.y, c = threadIdx.x;
  int b = bk >> 6, k = bk & 63;
  float s = 0.f;
  #pragma unroll
  for (int kc = 0; kc < 8; kc++)
    s += pp[(((size_t)kc*8 + b)*128 + side*64 + k)*256 + c];
  pool_bf_s[((size_t)side*512 + bk)*256 + c] = f2b(s);
}

// ---------------- MFMA attention (both sides, grid 1024) ----------------
__global__ __launch_bounds__(256) void k_attn2(
    const unsigned short* __restrict__ qq2, const unsigned short* __restrict__ kk2,
    const unsigned short* __restrict__ vvT2, unsigned short* __restrict__ obf2){
  __shared__ unsigned short sk[64*256];
  __shared__ unsigned short svT[256*64];
  __shared__ unsigned short sp[4][16*64];
  __shared__ unsigned short sow[4][16*32];
  int tid = threadIdx.x, w = tid >> 6, l = tid & 63;
  int blk = blockIdx.x;
  int side = (blk >= 512) ? 1 : 0;
  int lblk = blk - side*512;
  int b = lblk >> 6;
  int l15 = l & 15, lg = l >> 4;
  const uint4* ksrc = (const uint4*)(kk2 + ((size_t)side*512 + (size_t)b*64)*256);
  #pragma unroll
  for (int i = 0; i < 8; i++){
    int u = i*256 + tid;
    int row = u >> 5, j = u & 31;
    *(uint4*)&sk[row*256 + ((j ^ (row&7))<<3)] = ksrc[u];
  }
  const uint4* vsrc = (const uint4*)(vvT2 + ((size_t)side*B_ + b)*256*64);
  #pragma unroll
  for (int i = 0; i < 8; i++){
    int u = i*256 + tid;
    int row = u >> 3, j = u & 7;
    *(uint4*)&svT[row*64 + ((j ^ (row&7))<<3)] = vsrc[u];
  }
  __syncthreads();
  size_t qrow = (size_t)blk*64 + w*16 + l15;
  for (int h = 0; h < 8; h++){
    v8bf aq = *(const v8bf*)(qq2 + qrow*256 + h*32 + lg*8);
    f32x4 s[4];
    #pragma unroll
    for (int kt = 0; kt < 4; kt++){
      int row = kt*16 + l15;
      v8bf bk = *(const v8bf*)&sk[row*256 + (((h*4 + lg) ^ (row&7))<<3)];
      f32x4 z = {};
      s[kt] = __builtin_amdgcn_mfma_f32_16x16x32_bf16(aq, bk, z, 0, 0, 0);
    }
    #pragma unroll
    for (int r = 0; r < 4; r++){
      float v0 = s[0][r]*SCALE_, v1 = s[1][r]*SCALE_;
      float v2 = s[2][r]*SCALE_, v3 = s[3][r]*SCALE_;
      float mx = fmaxf(fmaxf(v0, v1), fmaxf(v2, v3));
      mx = fmaxf(mx, __shfl_xor(mx, 1));
      mx = fmaxf(mx, __shfl_xor(mx, 2));
      mx = fmaxf(mx, __shfl_xor(mx, 4));
      mx = fmaxf(mx, __shfl_xor(mx, 8));
      float e0 = __expf(v0-mx), e1 = __expf(v1-mx);
      float e2 = __expf(v2-mx), e3 = __expf(v3-mx);
      float sum = e0+e1+e2+e3;
      sum += __shfl_xor(sum, 1); sum += __shfl_xor(sum, 2);
      sum += __shfl_xor(sum, 4); sum += __shfl_xor(sum, 8);
      float inv = 1.0f/sum;
      s[0][r] = e0*inv; s[1][r] = e1*inv; s[2][r] = e2*inv; s[3][r] = e3*inv;
    }
    #pragma unroll
    for (int kt = 0; kt < 4; kt++){
      int colu = kt*2 + (l15>>3);
      #pragma unroll
      for (int r = 0; r < 4; r++){
        int row = lg*4 + r;
        sp[w][row*64 + ((colu ^ (row&7))<<3) + (l&7)] = f2b(s[kt][r]);
      }
    }
    f32x4 o[2] = {};
    #pragma unroll
    for (int k2 = 0; k2 < 2; k2++){
      v8bf pa = *(const v8bf*)&sp[w][l15*64 + (((k2*4 + lg) ^ (l15&7))<<3)];
      #pragma unroll
      for (int dt = 0; dt < 2; dt++){
        int vrow = h*32 + dt*16 + l15;
        v8bf bv = *(const v8bf*)&svT[vrow*64 + (((k2*4 + lg) ^ (vrow&7))<<3)];
        o[dt] = __builtin_amdgcn_mfma_f32_16x16x32_bf16(pa, bv, o[dt], 0, 0, 0);
      }
    }
    #pragma unroll
    for (int dt = 0; dt < 2; dt++)
      #pragma unroll
      for (int r = 0; r < 4; r++)
        sow[w][(lg*4 + r)*32 + dt*16 + l15] = f2b(o[dt][r]);
    uint4 ov = *(const uint4*)&sow[w][l15*32 + lg*8];
    *(uint4*)(obf2 + qrow*256 + h*32 + lg*8) = ov;
  }
}

// ---------------- residual + LayerNorm (n2, both sides) ----------------
__global__ __launch_bounds__(256) void k_ln2(
    const unsigned short* __restrict__ resid, const unsigned short* __restrict__ delta,
    const float* __restrict__ n2g, const float* __restrict__ n2b, int sl0,
    unsigned short* __restrict__ qout){
  int wv = threadIdx.x >> 6, l = threadIdx.x & 63;
  size_t m = (size_t)blockIdx.x*4 + wv;
  int side = (m >= (size_t)M_) ? 1 : 0;
  const float* g = n2g + (size_t)(sl0 + side*L_)*C_;
  const float* bta = n2b + (size_t)(sl0 + side*L_)*C_;
  uint2 dv = *(const uint2*)(delta + m*256 + l*4);
  float d0 = b2f((unsigned short)(dv.x & 0xffff)), d1 = b2f((unsigned short)(dv.x >> 16));
  float d2 = b2f((unsigned short)(dv.y & 0xffff)), d3 = b2f((unsigned short)(dv.y >> 16));
  uint2 rv = *(const uint2*)(resid + m*256 + l*4);
  float x0 = b2f((unsigned short)(rv.x & 0xffff)) + d0;
  float x1 = b2f((unsigned short)(rv.x >> 16)) + d1;
  float x2 = b2f((unsigned short)(rv.y & 0xffff)) + d2;
  float x3 = b2f((unsigned short)(rv.y >> 16)) + d3;
  float s = x0+x1+x2+x3;
  float ss = x0*x0+x1*x1+x2*x2+x3*x3;
  #pragma unroll
  for (int off = 32; off; off >>= 1){
    s  += __shfl_xor(s, off);
    ss += __shfl_xor(ss, off);
  }
  float mean = s * (1.0f/256.0f);
  float var = ss * (1.0f/256.0f) - mean*mean;
  float rstd = 1.0f / sqrtf(var + 1e-5f);
  float4 gv = *(const float4*)(g + l*4);
  float4 bv = *(const float4*)(bta + l*4);
  float y0 = (x0-mean)*rstd*gv.x + bv.x;
  float y1 = (x1-mean)*rstd*gv.y + bv.y;
  float y2 = (x2-mean)*rstd*gv.z + bv.z;
  float y3 = (x3-mean)*rstd*gv.w + bv.w;
  uint32_t p0 = (uint32_t)f2b(y0) | ((uint32_t)f2b(y1)<<16);
  uint32_t p1 = (uint32_t)f2b(y2) | ((uint32_t)f2b(y3)<<16);
  *(uint2*)(qout + m*256 + l*4) = make_uint2(p0,p1);
}

// ---------------- final select + transpose ----------------
__global__ __launch_bounds__(256) void k_select(
    const unsigned short* __restrict__ qA, const unsigned short* __restrict__ qB,
    const float* __restrict__ featT, const float* __restrict__ heat,
    const int* __restrict__ counts, float* __restrict__ out){
  __shared__ float t[32][33];
  int b = blockIdx.z;
  int n0 = blockIdx.x*32, c0 = blockIdx.y*32;
  int tx = threadIdx.x, ty = threadIdx.y;
  bool valid = (counts[b*2] > 0) && (counts[b*2+1] > 0);
  #pragma unroll
  for (int i = 0; i < 4; i++){
    int nl = ty*4+i;
    size_t m = (size_t)b*4096 + n0 + nl;
    float v;
    if (!valid) v = featT[m*256 + c0 + tx];
    else {
      bool fg = heat[(size_t)b*4096 + n0 + nl] >= 0.5f;
      v = fg ? b2f(qA[m*256 + c0 + tx]) : b2f(qB[m*256 + c0 + tx]);
    }
    t[nl][tx] = v;
  }
  __syncthreads();
  #pragma unroll
  for (int i = 0; i < 4; i++){
    int cl = ty*4+i;
    out[((size_t)b*256 + c0 + cl)*4096 + n0 + tx] = t[tx][cl];
  }
}

extern "C" void kernel_launch(void* const* d_in, const int* in_sizes, int n_in,
                              void* d_out, int out_size, void* d_ws, size_t ws_size,
                              hipStream_t stream){
  const float* x         = (const float*)d_in[0];
  const float* y         = (const float*)d_in[1];
  const float* proj_w    = (const float*)d_in[2];
  const float* proj_b    = (const float*)d_in[3];
  const float* sal_w     = (const float*)d_in[4];
  const float* sal_b     = (const float*)d_in[5];
  const float* soft_w    = (const float*)d_in[6];
  const float* soft_b    = (const float*)d_in[7];
  const float* attn_in_w = (const float*)d_in[8];
  const float* attn_in_b = (const float*)d_in[9];
  const float* attn_out_w= (const float*)d_in[10];
  const float* attn_out_b= (const float*)d_in[11];
  const float* n1_g      = (const float*)d_in[12];
  const float* n1_b      = (const float*)d_in[13];
  const float* ffn_w1    = (const float*)d_in[14];
  const float* ffn_b1    = (const float*)d_in[15];
  const float* ffn_w2    = (const float*)d_in[16];
  const float* ffn_b2    = (const float*)d_in[17];
  const float* n2_g      = (const float*)d_in[18];
  const float* n2_b      = (const float*)d_in[19];
  float* out = (float*)d_out;

  char* p = (char*)d_ws;
  auto alloc = [&](size_t bytes){ char* r = p; p += (bytes + 255) & ~(size_t)255; return r; };
  unsigned short* big0 = (unsigned short*)alloc((size_t)M2_*C_*2);
  unsigned short* xcT  = big0;
  unsigned short* qq2  = big0;
  float* featT = (float*)alloc((size_t)M_*C_*4);
  unsigned short* q2   = (unsigned short*)alloc((size_t)M2_*C_*2);
  unsigned short* swh  = q2;
  unsigned short* obf2 = (unsigned short*)alloc((size_t)M2_*C_*2);
  unsigned short* featC = obf2;
  unsigned short* featbf = (unsigned short*)alloc((size_t)M_*C_*2);
  unsigned short* tmpb2 = (unsigned short*)alloc((size_t)M2_*C_*2);
  float* g_all = (float*)tmpb2;
  float* pp    = (float*)alloc((size_t)8*8*128*256*4);
  double* salp = (double*)pp;
  unsigned short* pool_bf_s = (unsigned short*)alloc((size_t)2*512*256*2);
  unsigned short* kk2  = (unsigned short*)alloc((size_t)2*B_*K_*C_*2);
  unsigned short* vvT2 = (unsigned short*)alloc((size_t)2*B_*C_*K_*2);
  float* heat = (float*)alloc((size_t)B_*N_*4);
  double* u   = (double*)alloc(513*8);
  int* counts = (int*)alloc(64);
  float* zbias = (float*)alloc(512);
  unsigned short* projw_bf = (unsigned short*)alloc((size_t)C_*512*2);
  unsigned short* aiw_bf = (unsigned short*)alloc((size_t)2*L_*768*C_*2);
  unsigned short* f1w_bf = (unsigned short*)alloc((size_t)2*L_*FF_*C_*2);
  unsigned short* f2w_bf = (unsigned short*)alloc((size_t)2*L_*C_*FF_*2);
  unsigned short* aow_bf = (unsigned short*)alloc((size_t)2*L_*C_*C_*2);
  unsigned short* sw2_bf = (unsigned short*)alloc((size_t)2*K_*C_*2);

  hipMemsetAsync(counts, 0, 64, stream);
  hipMemsetAsync(zbias, 0, 512, stream);
  k_compute_u<<<1, 512, 0, stream>>>(sal_w, proj_w, proj_b, sal_b, u);
  k_sal_part<<<dim3(128, 16), 256, 0, stream>>>(x, y, u, salp);
  k_sal_red<<<128, 256, 0, stream>>>(salp, u, heat, counts);

  {
    int n0c = (int)((size_t)2*L_*FF_*C_);
    k_convall<<<dim3((unsigned)((n0c/4 + 255)/256), 6), 256, 0, stream>>>(
        ffn_w1, f1w_bf, n0c,
        ffn_w2, f2w_bf, (int)((size_t)2*L_*C_*FF_),
        attn_in_w, aiw_bf, (int)((size_t)2*L_*768*C_),
        attn_out_w, aow_bf, (int)((size_t)2*L_*C_*C_),
        proj_w, projw_bf, (int)((size_t)C_*512),
        soft_w, sw2_bf, (int)((size_t)2*K_*C_));
  }

  k_build_xcT<<<dim3(N_/32, 512/32, B_), dim3(32,8), 0, stream>>>(x, y, xcT);
  k_gemm_bt<0><<<dim3(M_/128, C_/128), 256, 0, stream>>>(xcT, projw_bf, proj_b, featT, M_, C_, 512);
  k_featmir<<<dim3(N_/32, C_/32, B_), dim3(32,8), 0, stream>>>(featT, featbf, featC);

  k_gemm_bt<0><<<dim3(M_/128, 1), 256, 0, stream>>>(featbf, sw2_bf, zbias, g_all, M_, 128, C_);
  k_swh<<<M_/64, 256, 0, stream>>>(g_all, heat, soft_b, swh);
  k_poolgemm<<<dim3(8, 2, B_), 256, 0, stream>>>(swh, featC, pp);
  k_pool2b<<<dim3(512, 2), 256, 0, stream>>>(pp, pool_bf_s);

  for (int lyr = 0; lyr < L_; ++lyr){
    const unsigned short* qin0 = (lyr == 0) ? featbf : q2;
    const unsigned short* qin1 = (lyr == 0) ? featbf : (q2 + (size_t)M_*C_);
    k_qkv<<<dim3(528, 2), 256, 0, stream>>>(qin0, qin1, pool_bf_s, aiw_bf, attn_in_b, lyr,
                                            qq2, kk2, vvT2);
    k_attn2<<<1024, 256, 0, stream>>>(qq2, kk2, vvT2, obf2);
    if (lyr == 0)
      k_gemm_ln<1><<<512, 512, 0, stream>>>(obf2, aow_bf, attn_out_b, featT, n1_g, n1_b, lyr, q2);
    else
      k_gemm_ln<0><<<512, 512, 0, stream>>>(obf2, aow_bf, attn_out_b, q2, n1_g, n1_b, lyr, q2);
    k_ffn<<<512, 512, 0, stream>>>(q2, f1w_bf, ffn_b1, f2w_bf, ffn_b2, lyr, tmpb2);
    k_ln2<<<M2_/4, 256, 0, stream>>>(q2, tmpb2, n2_g, n2_b, lyr, q2);
  }
  k_select<<<dim3(N_/32, C_/32, B_), dim3(32,8), 0, stream>>>(q2, q2 + (size_t)M_*C_, featT, heat, counts, out);
}